// Round 1
// baseline (864.843 us; speedup 1.0000x reference)
//
#include <hip/hip_runtime.h>
#include <hip/hip_bf16.h>

#define EPSF 1e-5f

__device__ __forceinline__ int seg_of(int i, int o0, int o1, int o2) {
    return (i >= o0) + (i >= o1) + (i >= o2);
}

// ---------------------------------------------------------------------------
// K0: fold BN scale/shift into weights; transpose pe_W2.  One block.
// ---------------------------------------------------------------------------
__global__ __launch_bounds__(256) void k_prep(
    const float* __restrict__ pe_W1, const float* __restrict__ pe_b1, const float* __restrict__ pe_bn,
    const float* __restrict__ pe_W2,
    const float* __restrict__ we_W1, const float* __restrict__ we_b1, const float* __restrict__ we_bn,
    const float* __restrict__ cg_W1, const float* __restrict__ cg_b1, const float* __restrict__ cg_bn,
    float* __restrict__ peW1f, float* __restrict__ peb1f, float* __restrict__ peW2T,
    float* __restrict__ weW1f, float* __restrict__ web1f,
    float* __restrict__ cgW1f, float* __restrict__ cgb1f)
{
    int t = threadIdx.x;
    __shared__ float sc1[64], sh1[64], csc[64], csh[64], wsc[8], wsh[8];
    if (t < 64) {
        float g = pe_bn[t], b = pe_bn[64+t], m = pe_bn[128+t], v = pe_bn[192+t];
        float s = g / sqrtf(v + EPSF);
        sc1[t] = s; sh1[t] = b - m * s;
        g = cg_bn[t]; b = cg_bn[64+t]; m = cg_bn[128+t]; v = cg_bn[192+t];
        s = g / sqrtf(v + EPSF);
        csc[t] = s; csh[t] = b - m * s;
    }
    if (t < 8) {
        float g = we_bn[t], b = we_bn[8+t], m = we_bn[16+t], v = we_bn[24+t];
        float s = g / sqrtf(v + EPSF);
        wsc[t] = s; wsh[t] = b - m * s;
    }
    __syncthreads();
    for (int u = t; u < 28*64; u += 256) { int j = u & 63; peW1f[u] = pe_W1[u] * sc1[j]; }
    if (t < 64) peb1f[t] = pe_b1[t] * sc1[t] + sh1[t];
    for (int u = t; u < 64*64; u += 256) { int j = u >> 6, c = u & 63; peW2T[c*64 + j] = pe_W2[u]; }
    for (int u = t; u < 64*8; u += 256) { int g = u & 7; weW1f[u] = we_W1[u] * wsc[g]; }
    if (t < 8) web1f[t] = we_b1[t] * wsc[t] + wsh[t];
    for (int u = t; u < 192*64; u += 256) { int c = u & 63; cgW1f[u] = cg_W1[u] * csc[c]; }
    if (t < 64) cgb1f[t] = cg_b1[t] * csc[t] + csh[t];
}

// ---------------------------------------------------------------------------
// K1: q/k/v projections + BN + relu (q,k) + per-segment max of q (atomics).
// Block = 256 threads = 64 cols x 4 slots; each slot handles 8 rows.
// Block covers 32 rows.  Grid = N/32.
// ---------------------------------------------------------------------------
__global__ __launch_bounds__(256) void k_qkv(
    const float* __restrict__ feat,
    const float* __restrict__ Wq, const float* __restrict__ bq, const float* __restrict__ bnq,
    const float* __restrict__ Wk, const float* __restrict__ bk, const float* __restrict__ bnk,
    const float* __restrict__ Wv, const float* __restrict__ bv,
    const int* __restrict__ offs,
    float* __restrict__ q_tbl, float* __restrict__ k_tbl, float* __restrict__ v_tbl,
    float* __restrict__ seg_max)
{
    int t = threadIdx.x;
    int c = t & 63, slot = t >> 6;
    float bqc = bq[c], bkc = bk[c], bvc = bv[c];
    float sq = bnq[c] / sqrtf(bnq[192+c] + EPSF); float tq = bnq[64+c] - bnq[128+c]*sq;
    float sk = bnk[c] / sqrtf(bnk[192+c] + EPSF); float tk = bnk[64+c] - bnk[128+c]*sk;
    int o0 = offs[0], o1 = offs[1], o2 = offs[2];
    int rblk = blockIdx.x * 32;
    int r0 = rblk + slot * 8;
    bool fast = seg_of(rblk, o0,o1,o2) == seg_of(rblk + 31, o0,o1,o2);

    float aq[8], ak[8], av[8];
    #pragma unroll
    for (int i = 0; i < 8; ++i) { aq[i] = bqc; ak[i] = bkc; av[i] = bvc; }

    const float* fbase = feat + r0 * 64;
    for (int j4 = 0; j4 < 16; ++j4) {
        float4 f[8];
        #pragma unroll
        for (int i = 0; i < 8; ++i) f[i] = *(const float4*)(fbase + i*64 + j4*4);
        #pragma unroll
        for (int jj = 0; jj < 4; ++jj) {
            int j = j4*4 + jj;
            float wq = Wq[j*64 + c], wk = Wk[j*64 + c], wv = Wv[j*64 + c];
            #pragma unroll
            for (int i = 0; i < 8; ++i) {
                float fv = (jj==0) ? f[i].x : (jj==1) ? f[i].y : (jj==2) ? f[i].z : f[i].w;
                aq[i] += fv * wq; ak[i] += fv * wk; av[i] += fv * wv;
            }
        }
    }
    float qmax = 0.f;
    #pragma unroll
    for (int i = 0; i < 8; ++i) {
        int r = r0 + i;
        float qv = fmaxf(aq[i]*sq + tq, 0.f);
        float kv = fmaxf(ak[i]*sk + tk, 0.f);
        q_tbl[r*64 + c] = qv; k_tbl[r*64 + c] = kv; v_tbl[r*64 + c] = av[i];
        if (fast) qmax = fmaxf(qmax, qv);
        else atomicMax((unsigned int*)&seg_max[seg_of(r,o0,o1,o2)*64 + c], __float_as_uint(qv));
    }
    if (fast) {
        __shared__ float sMax[4][64];
        sMax[slot][c] = qmax;
        __syncthreads();
        if (slot == 0) {
            float m = fmaxf(fmaxf(sMax[0][c], sMax[1][c]), fmaxf(sMax[2][c], sMax[3][c]));
            atomicMax((unsigned int*)&seg_max[seg_of(rblk,o0,o1,o2)*64 + c], __float_as_uint(m));
        }
    }
}

// ---------------------------------------------------------------------------
// K2a: neighbor_ctx[n][c] = max_k q[idx[n,k]][c].  Grid = N/32.
// ---------------------------------------------------------------------------
__global__ __launch_bounds__(256) void k_nctx(
    const float* __restrict__ q_tbl, const int* __restrict__ ridx, float* __restrict__ nctx)
{
    int t = threadIdx.x;
    int c = t & 63, slot = t >> 6;
    int n0 = blockIdx.x * 32 + slot * 8;
    for (int i = 0; i < 8; ++i) {
        int n = n0 + i;
        const int* ir = ridx + n * 16;
        float m = 0.f;  // q >= 0 post-relu
        #pragma unroll
        for (int kk = 0; kk < 16; ++kk) {
            int id = max(ir[kk], 0);
            m = fmaxf(m, q_tbl[id*64 + c]);
        }
        nctx[n*64 + c] = m;
    }
}

// ---------------------------------------------------------------------------
// K2b: gate = sigmoid(relu(bnfold([q,nctx,gctx] @ W1f + b1f)) @ W2 + b2).
// Same microkernel shape as K1.  Grid = N/32.
// ---------------------------------------------------------------------------
__global__ __launch_bounds__(256) void k_gate(
    const float* __restrict__ cgW1f, const float* __restrict__ cgb1f,
    const float* __restrict__ cg_W2, const float* __restrict__ cg_b2,
    const float* __restrict__ q_tbl, const float* __restrict__ nctx,
    const float* __restrict__ seg_max, const int* __restrict__ offs,
    float* __restrict__ gate)
{
    __shared__ float sh[32][68];
    int t = threadIdx.x;
    int c = t & 63, slot = t >> 6;
    int o0 = offs[0], o1 = offs[1], o2 = offs[2];
    int nb = blockIdx.x * 32;
    int p0 = slot * 8;

    float acc[8];
    float b1 = cgb1f[c];
    #pragma unroll
    for (int i = 0; i < 8; ++i) acc[i] = b1;

    // source 0: q rows (W1 rows 0..63)
    {
        const float* src = q_tbl + (nb + p0) * 64;
        for (int j4 = 0; j4 < 16; ++j4) {
            float4 f[8];
            #pragma unroll
            for (int i = 0; i < 8; ++i) f[i] = *(const float4*)(src + i*64 + j4*4);
            #pragma unroll
            for (int jj = 0; jj < 4; ++jj) {
                float w = cgW1f[(j4*4 + jj)*64 + c];
                #pragma unroll
                for (int i = 0; i < 8; ++i) {
                    float fv = (jj==0) ? f[i].x : (jj==1) ? f[i].y : (jj==2) ? f[i].z : f[i].w;
                    acc[i] += fv * w;
                }
            }
        }
    }
    // source 1: nctx rows (W1 rows 64..127)
    {
        const float* src = nctx + (nb + p0) * 64;
        for (int j4 = 0; j4 < 16; ++j4) {
            float4 f[8];
            #pragma unroll
            for (int i = 0; i < 8; ++i) f[i] = *(const float4*)(src + i*64 + j4*4);
            #pragma unroll
            for (int jj = 0; jj < 4; ++jj) {
                float w = cgW1f[(64 + j4*4 + jj)*64 + c];
                #pragma unroll
                for (int i = 0; i < 8; ++i) {
                    float fv = (jj==0) ? f[i].x : (jj==1) ? f[i].y : (jj==2) ? f[i].z : f[i].w;
                    acc[i] += fv * w;
                }
            }
        }
    }
    // source 2: global ctx rows (W1 rows 128..191)
    {
        int sg[8];
        #pragma unroll
        for (int i = 0; i < 8; ++i) sg[i] = seg_of(nb + p0 + i, o0, o1, o2);
        for (int j4 = 0; j4 < 16; ++j4) {
            float4 f[8];
            #pragma unroll
            for (int i = 0; i < 8; ++i) f[i] = *(const float4*)(seg_max + sg[i]*64 + j4*4);
            #pragma unroll
            for (int jj = 0; jj < 4; ++jj) {
                float w = cgW1f[(128 + j4*4 + jj)*64 + c];
                #pragma unroll
                for (int i = 0; i < 8; ++i) {
                    float fv = (jj==0) ? f[i].x : (jj==1) ? f[i].y : (jj==2) ? f[i].z : f[i].w;
                    acc[i] += fv * w;
                }
            }
        }
    }
    #pragma unroll
    for (int i = 0; i < 8; ++i) sh[p0 + i][c] = fmaxf(acc[i], 0.f);
    __syncthreads();
    // 32 points x 8 gates = 256 threads
    {
        int p = t >> 3, g = t & 7;
        float a = cg_b2[g];
        for (int j = 0; j < 64; ++j) a += sh[p][j] * cg_W2[j*8 + g];
        gate[(nb + p)*8 + g] = 1.f / (1.f + __expf(-a));
    }
}

// ---------------------------------------------------------------------------
// K3: per-(n,k): PE-MLP -> relation -> we-MLP -> geom; softmax over 16 lanes;
// einsum with gathered v.  Thread = one (n,k) pair; 16 pairs share a point.
// Grid = N/16 blocks of 256.
// ---------------------------------------------------------------------------
__global__ __launch_bounds__(256) void k_main(
    const float* __restrict__ coord, const int* __restrict__ ridx,
    const float* __restrict__ q_tbl, const float* __restrict__ k_tbl, const float* __restrict__ v_tbl,
    const float* __restrict__ peW1f, const float* __restrict__ peb1f,
    const float* __restrict__ peW2T, const float* __restrict__ pe_b2,
    const float* __restrict__ weW1f, const float* __restrict__ web1f,
    const float* __restrict__ we_W2, const float* __restrict__ we_b2,
    const float* __restrict__ gate, float* __restrict__ out)
{
    __shared__ float sXe[256][29];     // stride 29: conflict-free per-lane rows
    __shared__ float sAttn[16][16][8]; // [point-in-block][k][g]
    int t = threadIdx.x;
    int pair = blockIdx.x * 256 + t;
    int n = pair >> 4, kk = pair & 15;
    int pb = t >> 4;
    int id = ridx[pair];
    int ids = max(id, 0);

    float cx = coord[n*3], cy = coord[n*3+1], cz = coord[n*3+2];
    float dx = coord[ids*3]   - cx;
    float dy = coord[ids*3+1] - cy;
    float dz = coord[ids*3+2] - cz;
    float dist = sqrtf(dx*dx + dy*dy + dz*dz);

    float* xe = sXe[t];
    xe[0] = dx; xe[1] = dy; xe[2] = dz; xe[3] = dist;
    #pragma unroll
    for (int f = 0; f < 4; ++f) {
        float fr = (float)(3.14159265358979323846 * (double)(1 << f));
        float s, cv;
        __sincosf(dx * fr, &s, &cv); xe[4 + f*4 + 0] = s; xe[4 + f*4 + 2] = cv;
        __sincosf(dy * fr, &s, &cv); xe[4 + f*4 + 1] = s; xe[4 + f*4 + 3] = cv;
        __sincosf(dz * fr, &s, &cv); xe[20 + f*2 + 0] = s; xe[20 + f*2 + 1] = cv;
    }

    // phase 1: h = relu(xe @ W1f + b1f)   (BN folded)
    float h[64];
    #pragma unroll
    for (int j4 = 0; j4 < 16; ++j4) {
        float4 b = *(const float4*)(peb1f + j4*4);
        h[j4*4+0] = b.x; h[j4*4+1] = b.y; h[j4*4+2] = b.z; h[j4*4+3] = b.w;
    }
    for (int i = 0; i < 28; ++i) {
        float xi = xe[i];
        const float4* wrow = (const float4*)(peW1f + i*64);
        #pragma unroll
        for (int j4 = 0; j4 < 16; ++j4) {
            float4 w = wrow[j4];
            h[j4*4+0] += xi*w.x; h[j4*4+1] += xi*w.y; h[j4*4+2] += xi*w.z; h[j4*4+3] += xi*w.w;
        }
    }
    #pragma unroll
    for (int j = 0; j < 64; ++j) h[j] = fmaxf(h[j], 0.f);

    // phase 2: rel[c] = k[idx][c] - q[n][c] + (h @ W2T)[c] + b2[c];
    //          h2 += rel * we_W1f[c][:]
    float h2[8];
    {
        float4 a = *(const float4*)(web1f);
        float4 b = *(const float4*)(web1f + 4);
        h2[0]=a.x; h2[1]=a.y; h2[2]=a.z; h2[3]=a.w;
        h2[4]=b.x; h2[5]=b.y; h2[6]=b.z; h2[7]=b.w;
    }
    const float* krow = k_tbl + ids*64;
    const float* qrow = q_tbl + n*64;
    for (int c4 = 0; c4 < 16; ++c4) {
        float4 kv = *(const float4*)(krow + c4*4);
        float4 qv = *(const float4*)(qrow + c4*4);
        float4 bb = *(const float4*)(pe_b2 + c4*4);
        #pragma unroll
        for (int cc = 0; cc < 4; ++cc) {
            int c = c4*4 + cc;
            const float4* w2 = (const float4*)(peW2T + c*64);
            float a0 = 0.f, a1 = 0.f, a2 = 0.f, a3 = 0.f;
            #pragma unroll
            for (int j4 = 0; j4 < 16; ++j4) {
                float4 w = w2[j4];
                a0 += h[j4*4+0]*w.x; a1 += h[j4*4+1]*w.y;
                a2 += h[j4*4+2]*w.z; a3 += h[j4*4+3]*w.w;
            }
            float acc = (a0 + a1) + (a2 + a3);
            float kvv = (cc==0)?kv.x:(cc==1)?kv.y:(cc==2)?kv.z:kv.w;
            float qvv = (cc==0)?qv.x:(cc==1)?qv.y:(cc==2)?qv.z:qv.w;
            float bv2 = (cc==0)?bb.x:(cc==1)?bb.y:(cc==2)?bb.z:bb.w;
            float rel = kvv - qvv + acc + bv2;
            float4 wa = *(const float4*)(weW1f + c*8);
            float4 wb = *(const float4*)(weW1f + c*8 + 4);
            h2[0]+=rel*wa.x; h2[1]+=rel*wa.y; h2[2]+=rel*wa.z; h2[3]+=rel*wa.w;
            h2[4]+=rel*wb.x; h2[5]+=rel*wb.y; h2[6]+=rel*wb.z; h2[7]+=rel*wb.w;
        }
    }
    #pragma unroll
    for (int g = 0; g < 8; ++g) h2[g] = fmaxf(h2[g], 0.f);

    // geom = h2 @ we_W2 + we_b2
    float geom[8];
    {
        float4 a = *(const float4*)(we_b2);
        float4 b = *(const float4*)(we_b2 + 4);
        geom[0]=a.x; geom[1]=a.y; geom[2]=a.z; geom[3]=a.w;
        geom[4]=b.x; geom[5]=b.y; geom[6]=b.z; geom[7]=b.w;
    }
    #pragma unroll
    for (int g = 0; g < 8; ++g) {
        float4 a = *(const float4*)(we_W2 + g*8);
        float4 b = *(const float4*)(we_W2 + g*8 + 4);
        geom[0] += h2[g]*a.x; geom[1] += h2[g]*a.y; geom[2] += h2[g]*a.z; geom[3] += h2[g]*a.w;
        geom[4] += h2[g]*b.x; geom[5] += h2[g]*b.y; geom[6] += h2[g]*b.z; geom[7] += h2[g]*b.w;
    }

    // logits + per-g softmax over the 16 lanes of this point
    float4 g0 = *(const float4*)(gate + n*8);
    float4 g1 = *(const float4*)(gate + n*8 + 4);
    float gt[8] = {g0.x,g0.y,g0.z,g0.w,g1.x,g1.y,g1.z,g1.w};
    float maskf = (id >= 0) ? 1.f : ((id == -1) ? 0.f : -1.f);
    #pragma unroll
    for (int g = 0; g < 8; ++g) {
        float l = geom[g] * gt[g];
        float m = l;
        m = fmaxf(m, __shfl_xor(m, 1, 16));
        m = fmaxf(m, __shfl_xor(m, 2, 16));
        m = fmaxf(m, __shfl_xor(m, 4, 16));
        m = fmaxf(m, __shfl_xor(m, 8, 16));
        float e = __expf(l - m);
        float s = e;
        s += __shfl_xor(s, 1, 16);
        s += __shfl_xor(s, 2, 16);
        s += __shfl_xor(s, 4, 16);
        s += __shfl_xor(s, 8, 16);
        sAttn[pb][kk][g] = (e / s) * maskf;
    }
    __syncthreads();

    // out[n][kk*4 .. kk*4+3] = sum_k2 attn[k2][g] * v[idx[n,k2]][kk*4..]
    const int* irow = ridx + n*16;
    float4 o = make_float4(0.f, 0.f, 0.f, 0.f);
    int ghalf = kk >> 1;  // g = (kk*4)/8, constant over the 4 output cols
    #pragma unroll
    for (int k2 = 0; k2 < 16; ++k2) {
        int id2 = max(irow[k2], 0);
        float a = sAttn[pb][k2][ghalf];
        float4 vv = *(const float4*)(v_tbl + id2*64 + kk*4);
        o.x += a*vv.x; o.y += a*vv.y; o.z += a*vv.z; o.w += a*vv.w;
    }
    *(float4*)(out + n*64 + kk*4) = o;
}

// ---------------------------------------------------------------------------
extern "C" void kernel_launch(void* const* d_in, const int* in_sizes, int n_in,
                              void* d_out, int out_size, void* d_ws, size_t ws_size,
                              hipStream_t stream)
{
    const float* feat  = (const float*)d_in[0];
    const float* coord = (const float*)d_in[1];
    const int*   ridx  = (const int*)d_in[2];
    const int*   offs  = (const int*)d_in[3];
    const float* Wq = (const float*)d_in[4];  const float* bq = (const float*)d_in[5];  const float* bnq = (const float*)d_in[6];
    const float* Wk = (const float*)d_in[7];  const float* bk = (const float*)d_in[8];  const float* bnk = (const float*)d_in[9];
    const float* Wv = (const float*)d_in[10]; const float* bv = (const float*)d_in[11];
    const float* pe_W1 = (const float*)d_in[12]; const float* pe_b1 = (const float*)d_in[13]; const float* pe_bn = (const float*)d_in[14];
    const float* pe_W2 = (const float*)d_in[15]; const float* pe_b2 = (const float*)d_in[16];
    const float* we_W1 = (const float*)d_in[17]; const float* we_b1 = (const float*)d_in[18]; const float* we_bn = (const float*)d_in[19];
    const float* we_W2 = (const float*)d_in[20]; const float* we_b2 = (const float*)d_in[21];
    const float* cg_W1 = (const float*)d_in[22]; const float* cg_b1 = (const float*)d_in[23]; const float* cg_bn = (const float*)d_in[24];
    const float* cg_W2 = (const float*)d_in[25]; const float* cg_b2 = (const float*)d_in[26];
    float* out = (float*)d_out;
    int N = in_sizes[0] / 64;

    float* ws = (float*)d_ws;
    float* q_tbl = ws;                       // N*64
    float* k_tbl = q_tbl + (size_t)N*64;     // N*64
    float* v_tbl = k_tbl + (size_t)N*64;     // N*64
    float* nctx  = v_tbl + (size_t)N*64;     // N*64
    float* gatep = nctx + (size_t)N*64;      // N*8
    float* segm  = gatep + (size_t)N*8;      // 4*64
    float* peW1f = segm + 256;               // 28*64
    float* peb1f = peW1f + 1792;             // 64
    float* peW2T = peb1f + 64;               // 64*64
    float* weW1f = peW2T + 4096;             // 64*8
    float* web1f = weW1f + 512;              // 8
    float* cgW1f = web1f + 8;                // 192*64
    float* cgb1f = cgW1f + 12288;            // 64

    hipMemsetAsync(segm, 0, 256 * sizeof(float), stream);
    k_prep<<<1, 256, 0, stream>>>(pe_W1, pe_b1, pe_bn, pe_W2, we_W1, we_b1, we_bn,
                                  cg_W1, cg_b1, cg_bn,
                                  peW1f, peb1f, peW2T, weW1f, web1f, cgW1f, cgb1f);
    k_qkv<<<N/32, 256, 0, stream>>>(feat, Wq, bq, bnq, Wk, bk, bnk, Wv, bv, offs,
                                    q_tbl, k_tbl, v_tbl, segm);
    k_nctx<<<N/32, 256, 0, stream>>>(q_tbl, ridx, nctx);
    k_gate<<<N/32, 256, 0, stream>>>(cgW1f, cgb1f, cg_W2, cg_b2, q_tbl, nctx, segm, offs, gatep);
    k_main<<<N/16, 256, 0, stream>>>(coord, ridx, q_tbl, k_tbl, v_tbl,
                                     peW1f, peb1f, peW2T, pe_b2,
                                     weW1f, web1f, we_W2, we_b2, gatep, out);
}

// Round 2
// 474.651 us; speedup vs baseline: 1.8221x; 1.8221x over previous
//
#include <hip/hip_runtime.h>
#include <hip/hip_bf16.h>

#define EPSF 1e-5f

typedef __attribute__((ext_vector_type(8))) short short8;
typedef __attribute__((ext_vector_type(4))) float f32x4;

__device__ __forceinline__ int seg_of(int i, int o0, int o1, int o2) {
    return (i >= o0) + (i >= o1) + (i >= o2);
}

__device__ __forceinline__ unsigned short f2bf(float f) {
    unsigned int u = __float_as_uint(f);
    unsigned int r = (u + 0x7fffu + ((u >> 16) & 1u)) >> 16;
    return (unsigned short)r;
}
__device__ __forceinline__ unsigned int pack2bf(float a, float b) {
    return (unsigned int)f2bf(a) | ((unsigned int)f2bf(b) << 16);
}

// ---------------------------------------------------------------------------
// K0: fold BNs, build Wc = pe_W2 @ we_W1f, cvec, and bf16 MFMA B-fragments.
// ---------------------------------------------------------------------------
__global__ __launch_bounds__(256) void k_prep(
    const float* __restrict__ pe_W1, const float* __restrict__ pe_b1, const float* __restrict__ pe_bn,
    const float* __restrict__ pe_W2, const float* __restrict__ pe_b2,
    const float* __restrict__ we_W1, const float* __restrict__ we_b1, const float* __restrict__ we_bn,
    const float* __restrict__ we_W2,
    const float* __restrict__ cg_W1, const float* __restrict__ cg_b1, const float* __restrict__ cg_bn,
    float* __restrict__ peb1f, float* __restrict__ cvecg,
    float* __restrict__ weW1f,
    float* __restrict__ cgW1f, float* __restrict__ cgb1f,
    unsigned short* __restrict__ W1frag, unsigned short* __restrict__ Wcfrag,
    unsigned short* __restrict__ W2frag)
{
    int t = threadIdx.x;
    __shared__ float sc1[64], ssh1[64], csc[64], csh[64], wsc[8], wsh[8];
    __shared__ float sWe[64][8], sWc[64][8], sWb[8];
    if (t < 64) {
        float g = pe_bn[t], b = pe_bn[64+t], m = pe_bn[128+t], v = pe_bn[192+t];
        float s = g / sqrtf(v + EPSF);
        sc1[t] = s; ssh1[t] = b - m * s;
        g = cg_bn[t]; b = cg_bn[64+t]; m = cg_bn[128+t]; v = cg_bn[192+t];
        s = g / sqrtf(v + EPSF);
        csc[t] = s; csh[t] = b - m * s;
    }
    if (t < 8) {
        float g = we_bn[t], b = we_bn[8+t], m = we_bn[16+t], v = we_bn[24+t];
        float s = g / sqrtf(v + EPSF);
        wsc[t] = s; wsh[t] = b - m * s;
    }
    __syncthreads();
    for (int u = t; u < 512; u += 256) {
        int g = u & 7;
        float v = we_W1[u] * wsc[g];
        weW1f[u] = v; sWe[u >> 3][g] = v;
    }
    if (t < 8) sWb[t] = we_b1[t] * wsc[t] + wsh[t];
    if (t < 64) peb1f[t] = pe_b1[t] * sc1[t] + ssh1[t];
    for (int u = t; u < 192*64; u += 256) { int c = u & 63; cgW1f[u] = cg_W1[u] * csc[c]; }
    if (t < 64) cgb1f[t] = cg_b1[t] * csc[t] + csh[t];
    __syncthreads();
    for (int u = t; u < 512; u += 256) {
        int h = u >> 3, g = u & 7;
        float a = 0.f;
        for (int c = 0; c < 64; ++c) a += pe_W2[h*64 + c] * sWe[c][g];
        sWc[h][g] = a;
    }
    if (t < 8) {
        float a = sWb[t];
        for (int c = 0; c < 64; ++c) a += pe_b2[c] * sWe[c][t];
        cvecg[t] = a;
    }
    __syncthreads();
    // W1frag: B-frag for mfma 16x16x32: lane l holds col=16ct+(l&15), k=(l>>4)*8+j
    {
        int ct = t >> 6, l = t & 63;
        int col = 16*ct + (l & 15), kg = l >> 4;
        #pragma unroll
        for (int j = 0; j < 8; ++j) {
            int k = kg*8 + j;
            float v = (k < 28) ? pe_W1[k*64 + col] * sc1[col] : 0.f;
            W1frag[ct*512 + l*8 + j] = f2bf(v);
        }
    }
    if (t < 128) {
        int kg = t >> 6, l = t & 63, g = l & 15;
        #pragma unroll
        for (int j = 0; j < 8; ++j) {
            int k = kg*32 + (l >> 4)*8 + j;
            float v = (g < 8) ? sWc[k][g] : 0.f;
            Wcfrag[kg*512 + l*8 + j] = f2bf(v);
        }
    }
    if (t < 64) {
        int l = t, g = l & 15;
        #pragma unroll
        for (int j = 0; j < 8; ++j) {
            float v = (l < 16 && g < 8 && j < 8) ? we_W2[j*8 + g] : 0.f;
            W2frag[l*8 + j] = f2bf(v);
        }
    }
}

// ---------------------------------------------------------------------------
// K1: q/v projections + BN/relu + seg-max(q) + kw/qw = {k,q} @ we_W1f.
// k_tbl is never materialized (only kw needed downstream).
// ---------------------------------------------------------------------------
__global__ __launch_bounds__(256) void k_qkv(
    const float* __restrict__ feat,
    const float* __restrict__ Wq, const float* __restrict__ bq, const float* __restrict__ bnq,
    const float* __restrict__ Wk, const float* __restrict__ bk, const float* __restrict__ bnk,
    const float* __restrict__ Wv, const float* __restrict__ bv,
    const int* __restrict__ offs, const float* __restrict__ weW1f,
    float* __restrict__ q_tbl, float* __restrict__ v_tbl,
    float* __restrict__ seg_max, float* __restrict__ kw, float* __restrict__ qw)
{
    __shared__ float sQ[32][68], sK[32][68], sWeL[64][8], sMax[4][64];
    int t = threadIdx.x;
    int c = t & 63, slot = t >> 6;
    float bqc = bq[c], bkc = bk[c], bvc = bv[c];
    float sq = bnq[c] / sqrtf(bnq[192+c] + EPSF); float tq = bnq[64+c] - bnq[128+c]*sq;
    float sk = bnk[c] / sqrtf(bnk[192+c] + EPSF); float tk = bnk[64+c] - bnk[128+c]*sk;
    int o0 = offs[0], o1 = offs[1], o2 = offs[2];
    int rblk = blockIdx.x * 32;
    int r0 = rblk + slot * 8;
    bool fast = seg_of(rblk, o0,o1,o2) == seg_of(rblk + 31, o0,o1,o2);

    float aq[8], ak[8], av[8];
    #pragma unroll
    for (int i = 0; i < 8; ++i) { aq[i] = bqc; ak[i] = bkc; av[i] = bvc; }

    const float* fbase = feat + (size_t)r0 * 64;
    for (int j4 = 0; j4 < 16; ++j4) {
        float4 f[8];
        #pragma unroll
        for (int i = 0; i < 8; ++i) f[i] = *(const float4*)(fbase + i*64 + j4*4);
        #pragma unroll
        for (int jj = 0; jj < 4; ++jj) {
            int j = j4*4 + jj;
            float wq = Wq[j*64 + c], wk = Wk[j*64 + c], wv = Wv[j*64 + c];
            #pragma unroll
            for (int i = 0; i < 8; ++i) {
                float fv = (jj==0) ? f[i].x : (jj==1) ? f[i].y : (jj==2) ? f[i].z : f[i].w;
                aq[i] += fv * wq; ak[i] += fv * wk; av[i] += fv * wv;
            }
        }
    }
    float qmax = 0.f;
    #pragma unroll
    for (int i = 0; i < 8; ++i) {
        int r = r0 + i;
        float qv = fmaxf(aq[i]*sq + tq, 0.f);
        float kv = fmaxf(ak[i]*sk + tk, 0.f);
        q_tbl[(size_t)r*64 + c] = qv; v_tbl[(size_t)r*64 + c] = av[i];
        sQ[slot*8 + i][c] = qv; sK[slot*8 + i][c] = kv;
        if (fast) qmax = fmaxf(qmax, qv);
        else atomicMax((unsigned int*)&seg_max[seg_of(r,o0,o1,o2)*64 + c], __float_as_uint(qv));
    }
    if (fast) {
        sMax[slot][c] = qmax;
        __syncthreads();
        if (slot == 0) {
            float m = fmaxf(fmaxf(sMax[0][c], sMax[1][c]), fmaxf(sMax[2][c], sMax[3][c]));
            atomicMax((unsigned int*)&seg_max[seg_of(rblk,o0,o1,o2)*64 + c], __float_as_uint(m));
        }
    }
    for (int u = t; u < 512; u += 256) sWeL[u >> 3][u & 7] = weW1f[u];
    __syncthreads();
    {
        int p = t >> 3, gg = t & 7;
        float kwv = 0.f, qwv = 0.f;
        for (int j = 0; j < 64; ++j) {
            float wj = sWeL[j][gg];
            kwv += sK[p][j] * wj; qwv += sQ[p][j] * wj;
        }
        kw[(size_t)(rblk + p)*8 + gg] = kwv;
        qw[(size_t)(rblk + p)*8 + gg] = qwv;
    }
}

// ---------------------------------------------------------------------------
// K2a: neighbor_ctx[n][c] = max_k q[idx[n,k]][c].
// ---------------------------------------------------------------------------
__global__ __launch_bounds__(256) void k_nctx(
    const float* __restrict__ q_tbl, const int* __restrict__ ridx, float* __restrict__ nctx)
{
    int t = threadIdx.x;
    int c = t & 63, slot = t >> 6;
    int n0 = blockIdx.x * 32 + slot * 8;
    for (int i = 0; i < 8; ++i) {
        int n = n0 + i;
        const int* ir = ridx + (size_t)n * 16;
        float m = 0.f;
        #pragma unroll
        for (int kk = 0; kk < 16; ++kk) {
            int id = max(ir[kk], 0);
            m = fmaxf(m, q_tbl[(size_t)id*64 + c]);
        }
        nctx[(size_t)n*64 + c] = m;
    }
}

// ---------------------------------------------------------------------------
// K2b: gate MLP (unchanged fp32).
// ---------------------------------------------------------------------------
__global__ __launch_bounds__(256) void k_gate(
    const float* __restrict__ cgW1f, const float* __restrict__ cgb1f,
    const float* __restrict__ cg_W2, const float* __restrict__ cg_b2,
    const float* __restrict__ q_tbl, const float* __restrict__ nctx,
    const float* __restrict__ seg_max, const int* __restrict__ offs,
    float* __restrict__ gate)
{
    __shared__ float sh[32][68];
    int t = threadIdx.x;
    int c = t & 63, slot = t >> 6;
    int o0 = offs[0], o1 = offs[1], o2 = offs[2];
    int nb = blockIdx.x * 32;
    int p0 = slot * 8;

    float acc[8];
    float b1 = cgb1f[c];
    #pragma unroll
    for (int i = 0; i < 8; ++i) acc[i] = b1;

    {
        const float* src = q_tbl + (size_t)(nb + p0) * 64;
        for (int j4 = 0; j4 < 16; ++j4) {
            float4 f[8];
            #pragma unroll
            for (int i = 0; i < 8; ++i) f[i] = *(const float4*)(src + i*64 + j4*4);
            #pragma unroll
            for (int jj = 0; jj < 4; ++jj) {
                float w = cgW1f[(j4*4 + jj)*64 + c];
                #pragma unroll
                for (int i = 0; i < 8; ++i) {
                    float fv = (jj==0) ? f[i].x : (jj==1) ? f[i].y : (jj==2) ? f[i].z : f[i].w;
                    acc[i] += fv * w;
                }
            }
        }
    }
    {
        const float* src = nctx + (size_t)(nb + p0) * 64;
        for (int j4 = 0; j4 < 16; ++j4) {
            float4 f[8];
            #pragma unroll
            for (int i = 0; i < 8; ++i) f[i] = *(const float4*)(src + i*64 + j4*4);
            #pragma unroll
            for (int jj = 0; jj < 4; ++jj) {
                float w = cgW1f[(64 + j4*4 + jj)*64 + c];
                #pragma unroll
                for (int i = 0; i < 8; ++i) {
                    float fv = (jj==0) ? f[i].x : (jj==1) ? f[i].y : (jj==2) ? f[i].z : f[i].w;
                    acc[i] += fv * w;
                }
            }
        }
    }
    {
        int sg[8];
        #pragma unroll
        for (int i = 0; i < 8; ++i) sg[i] = seg_of(nb + p0 + i, o0, o1, o2);
        for (int j4 = 0; j4 < 16; ++j4) {
            float4 f[8];
            #pragma unroll
            for (int i = 0; i < 8; ++i) f[i] = *(const float4*)(seg_max + sg[i]*64 + j4*4);
            #pragma unroll
            for (int jj = 0; jj < 4; ++jj) {
                float w = cgW1f[(128 + j4*4 + jj)*64 + c];
                #pragma unroll
                for (int i = 0; i < 8; ++i) {
                    float fv = (jj==0) ? f[i].x : (jj==1) ? f[i].y : (jj==2) ? f[i].z : f[i].w;
                    acc[i] += fv * w;
                }
            }
        }
    }
    #pragma unroll
    for (int i = 0; i < 8; ++i) sh[p0 + i][c] = fmaxf(acc[i], 0.f);
    __syncthreads();
    {
        int p = t >> 3, g = t & 7;
        float a = cg_b2[g];
        for (int j = 0; j < 64; ++j) a += sh[p][j] * cg_W2[j*8 + g];
        gate[(size_t)(nb + p)*8 + g] = 1.f / (1.f + __expf(-a));
    }
}

// ---------------------------------------------------------------------------
// K3: MFMA pipeline. 1 wave / block; 64 pairs = 4 points. All LDS wave-local.
// phase1: H1 = relu(Xe[64x28bf16] @ W1frag)          (16 MFMA)
// phase2: H2 = relu(H1 @ Wc + (kw[idx]-qw+cvec))     (8 MFMA)
// phase3: geom = H2 @ we_W2 + b2; softmax; einsum.   (4 MFMA)
// ---------------------------------------------------------------------------
__global__ __launch_bounds__(64, 3) void k_main(
    const float* __restrict__ coord, const int* __restrict__ ridx,
    const float* __restrict__ v_tbl,
    const float* __restrict__ kw, const float* __restrict__ qw,
    const float* __restrict__ gate,
    const float* __restrict__ peb1f, const float* __restrict__ cvecg,
    const float* __restrict__ we_b2,
    const unsigned short* __restrict__ W1frag, const unsigned short* __restrict__ Wcfrag,
    const unsigned short* __restrict__ W2frag,
    float* __restrict__ out)
{
    __shared__ __align__(16) unsigned short sA1[64*40];  // xe bf16, stride 40 (2-way free)
    __shared__ __align__(16) unsigned short sA2[64*72];  // H1 bf16, stride 72 (2-way free)
    __shared__ __align__(16) unsigned short sAh2[16*8];  // h2 tile, reused per rt
    __shared__ float sAttn[4][16][8];
    __shared__ int sIds[64];

    int l = threadIdx.x;
    int pair = blockIdx.x * 64 + l;
    int nself = pair >> 4;

    int id = ridx[pair];
    sIds[l] = id;
    int ids = max(id, 0);

    // --- xe features -> sA1 (bf16, packed dword writes) ---
    {
        float cx = coord[nself*3], cy = coord[nself*3+1], cz = coord[nself*3+2];
        float dx = coord[ids*3]   - cx;
        float dy = coord[ids*3+1] - cy;
        float dz = coord[ids*3+2] - cz;
        float dist = sqrtf(dx*dx + dy*dy + dz*dz);
        unsigned int* row = (unsigned int*)sA1 + l*20;
        row[0] = pack2bf(dx, dy);
        row[1] = pack2bf(dz, dist);
        #pragma unroll
        for (int fi = 0; fi < 4; ++fi) {
            float fr = 3.14159265358979f * (float)(1 << fi);
            float sx, cxx, sy, cyy, sz, czz;
            __sincosf(dx * fr, &sx, &cxx);
            __sincosf(dy * fr, &sy, &cyy);
            __sincosf(dz * fr, &sz, &czz);
            row[2 + 2*fi] = pack2bf(sx, sy);
            row[3 + 2*fi] = pack2bf(cxx, cyy);
            row[10 + fi]  = pack2bf(sz, czz);
        }
        row[14] = 0u; row[15] = 0u;
    }

    int lc = l & 15, lg = l >> 4;

    // hoisted B-fragments and per-lane constants
    short8 bW1[4], bWc[2], bW2;
    #pragma unroll
    for (int ct = 0; ct < 4; ++ct) bW1[ct] = *(const short8*)(W1frag + ct*512 + l*8);
    bWc[0] = *(const short8*)(Wcfrag + l*8);
    bWc[1] = *(const short8*)(Wcfrag + 512 + l*8);
    bW2 = *(const short8*)(W2frag + l*8);

    float bias1[4];
    #pragma unroll
    for (int ct = 0; ct < 4; ++ct) bias1[ct] = peb1f[16*ct + lc];
    int g7 = lc & 7;
    float cvec_g = cvecg[g7];
    float bias3 = we_b2[g7];

    #pragma unroll
    for (int rt = 0; rt < 4; ++rt) {
        int n = blockIdx.x * 4 + rt;
        // ---- phase 1: 4 MFMA over K=32 ----
        short8 a1 = *(const short8*)(sA1 + (rt*16 + lc)*40 + lg*8);
        f32x4 c1[4];
        #pragma unroll
        for (int ct = 0; ct < 4; ++ct) {
            f32x4 z = {0.f, 0.f, 0.f, 0.f};
            c1[ct] = __builtin_amdgcn_mfma_f32_16x16x32_bf16(a1, bW1[ct], z, 0, 0, 0);
        }
        // epilogue: bias+relu -> bf16 -> sA2 rows (C layout: col=lc, row=lg*4+reg)
        #pragma unroll
        for (int ct = 0; ct < 4; ++ct) {
            #pragma unroll
            for (int reg = 0; reg < 4; ++reg) {
                int r = rt*16 + lg*4 + reg;
                float h1 = fmaxf(c1[ct][reg] + bias1[ct], 0.f);
                sA2[r*72 + 16*ct + lc] = f2bf(h1);
            }
        }
        // ---- phase 2: init acc with kw gather - qw + cvec; 2 MFMA over K=64 ----
        int ids_r[4];
        #pragma unroll
        for (int reg = 0; reg < 4; ++reg) ids_r[reg] = sIds[rt*16 + lg*4 + reg];
        float qwv = qw[(size_t)n*8 + g7];
        f32x4 c2;
        #pragma unroll
        for (int reg = 0; reg < 4; ++reg)
            c2[reg] = kw[(size_t)max(ids_r[reg],0)*8 + g7] - qwv + cvec_g;
        short8 a20 = *(const short8*)(sA2 + (rt*16 + lc)*72 + lg*8);
        short8 a21 = *(const short8*)(sA2 + (rt*16 + lc)*72 + 32 + lg*8);
        c2 = __builtin_amdgcn_mfma_f32_16x16x32_bf16(a20, bWc[0], c2, 0, 0, 0);
        c2 = __builtin_amdgcn_mfma_f32_16x16x32_bf16(a21, bWc[1], c2, 0, 0, 0);
        // h2 -> sAh2
        if (lc < 8) {
            #pragma unroll
            for (int reg = 0; reg < 4; ++reg)
                sAh2[(lg*4 + reg)*8 + lc] = f2bf(fmaxf(c2[reg], 0.f));
        }
        // ---- phase 3: geom = h2 @ we_W2 + b2 (1 MFMA, K=8 in group 0) ----
        short8 a3 = {0,0,0,0,0,0,0,0};
        if (l < 16) a3 = *(const short8*)(sAh2 + lc*8);
        f32x4 c3;
        #pragma unroll
        for (int reg = 0; reg < 4; ++reg) c3[reg] = bias3;
        c3 = __builtin_amdgcn_mfma_f32_16x16x32_bf16(a3, bW2, c3, 0, 0, 0);
        // ---- softmax over the 16 rows of this point ----
        float gv = gate[(size_t)n*8 + g7];
        float lgt[4];
        #pragma unroll
        for (int reg = 0; reg < 4; ++reg) lgt[reg] = c3[reg] * gv;
        float m = fmaxf(fmaxf(lgt[0], lgt[1]), fmaxf(lgt[2], lgt[3]));
        m = fmaxf(m, __shfl_xor(m, 16));
        m = fmaxf(m, __shfl_xor(m, 32));
        float e[4], s = 0.f;
        #pragma unroll
        for (int reg = 0; reg < 4; ++reg) { e[reg] = __expf(lgt[reg] - m); s += e[reg]; }
        s += __shfl_xor(s, 16);
        s += __shfl_xor(s, 32);
        float inv = 1.f / s;
        if (lc < 8) {
            #pragma unroll
            for (int reg = 0; reg < 4; ++reg) {
                int idv = ids_r[reg];
                float mf = (idv >= 0) ? 1.f : ((idv == -1) ? 0.f : -1.f);
                sAttn[rt][lg*4 + reg][lc] = e[reg] * inv * mf;
            }
        }
    }

    // ---- einsum: lane = (point p, col-block kk) ----
    {
        int p = lg, kk = lc;
        int n2 = blockIdx.x * 4 + p;
        float4 o = make_float4(0.f, 0.f, 0.f, 0.f);
        int gh = kk >> 1;
        #pragma unroll
        for (int k2 = 0; k2 < 16; ++k2) {
            int id2 = max(sIds[p*16 + k2], 0);
            float a = sAttn[p][k2][gh];
            float4 vv = *(const float4*)(v_tbl + (size_t)id2*64 + kk*4);
            o.x += a*vv.x; o.y += a*vv.y; o.z += a*vv.z; o.w += a*vv.w;
        }
        *(float4*)(out + (size_t)n2*64 + kk*4) = o;
    }
}

// ---------------------------------------------------------------------------
extern "C" void kernel_launch(void* const* d_in, const int* in_sizes, int n_in,
                              void* d_out, int out_size, void* d_ws, size_t ws_size,
                              hipStream_t stream)
{
    const float* feat  = (const float*)d_in[0];
    const float* coord = (const float*)d_in[1];
    const int*   ridx  = (const int*)d_in[2];
    const int*   offs  = (const int*)d_in[3];
    const float* Wq = (const float*)d_in[4];  const float* bq = (const float*)d_in[5];  const float* bnq = (const float*)d_in[6];
    const float* Wk = (const float*)d_in[7];  const float* bk = (const float*)d_in[8];  const float* bnk = (const float*)d_in[9];
    const float* Wv = (const float*)d_in[10]; const float* bv = (const float*)d_in[11];
    const float* pe_W1 = (const float*)d_in[12]; const float* pe_b1 = (const float*)d_in[13]; const float* pe_bn = (const float*)d_in[14];
    const float* pe_W2 = (const float*)d_in[15]; const float* pe_b2 = (const float*)d_in[16];
    const float* we_W1 = (const float*)d_in[17]; const float* we_b1 = (const float*)d_in[18]; const float* we_bn = (const float*)d_in[19];
    const float* we_W2 = (const float*)d_in[20]; const float* we_b2 = (const float*)d_in[21];
    const float* cg_W1 = (const float*)d_in[22]; const float* cg_b1 = (const float*)d_in[23]; const float* cg_bn = (const float*)d_in[24];
    const float* cg_W2 = (const float*)d_in[25]; const float* cg_b2 = (const float*)d_in[26];
    float* out = (float*)d_out;
    int N = in_sizes[0] / 64;

    float* ws = (float*)d_ws;
    float* q_tbl = ws;                        // N*64
    float* v_tbl = q_tbl + (size_t)N*64;      // N*64
    float* nctx  = v_tbl + (size_t)N*64;      // N*64
    float* gatep = nctx + (size_t)N*64;       // N*8
    float* kwp   = gatep + (size_t)N*8;       // N*8
    float* qwp   = kwp + (size_t)N*8;         // N*8
    float* segm  = qwp + (size_t)N*8;         // 256
    float* peb1f = segm + 256;                // 64
    float* cvecg = peb1f + 64;                // 8
    float* weW1f = cvecg + 8;                 // 512
    float* cgW1f = weW1f + 512;               // 12288
    float* cgb1f = cgW1f + 12288;             // 64
    unsigned short* W1frag = (unsigned short*)(cgb1f + 64);  // 2048 ush
    unsigned short* Wcfrag = W1frag + 2048;                  // 1024 ush
    unsigned short* W2frag = Wcfrag + 1024;                  // 512 ush

    hipMemsetAsync(segm, 0, 256 * sizeof(float), stream);
    k_prep<<<1, 256, 0, stream>>>(pe_W1, pe_b1, pe_bn, pe_W2, pe_b2,
                                  we_W1, we_b1, we_bn, we_W2,
                                  cg_W1, cg_b1, cg_bn,
                                  peb1f, cvecg, weW1f, cgW1f, cgb1f,
                                  W1frag, Wcfrag, W2frag);
    k_qkv<<<N/32, 256, 0, stream>>>(feat, Wq, bq, bnq, Wk, bk, bnk, Wv, bv, offs, weW1f,
                                    q_tbl, v_tbl, segm, kwp, qwp);
    k_nctx<<<N/32, 256, 0, stream>>>(q_tbl, ridx, nctx);
    k_gate<<<N/32, 256, 0, stream>>>(cgW1f, cgb1f, cg_W2, cg_b2, q_tbl, nctx, segm, offs, gatep);
    k_main<<<N/4, 64, 0, stream>>>(coord, ridx, v_tbl, kwp, qwp, gatep,
                                   peb1f, cvecg, we_b2,
                                   W1frag, Wcfrag, W2frag, out);
}

// Round 3
// 138.714 us; speedup vs baseline: 6.2347x; 3.4218x over previous
//
#include <hip/hip_runtime.h>
#include <hip/hip_bf16.h>

#define EPSF 1e-5f

typedef __attribute__((ext_vector_type(8))) short short8;
typedef __attribute__((ext_vector_type(4))) float f32x4;

__device__ __forceinline__ int seg_of(int i, int o0, int o1, int o2) {
    return (i >= o0) + (i >= o1) + (i >= o2);
}

__device__ __forceinline__ unsigned short f2bf(float f) {
    unsigned int u = __float_as_uint(f);
    unsigned int r = (u + 0x7fffu + ((u >> 16) & 1u)) >> 16;
    return (unsigned short)r;
}
__device__ __forceinline__ unsigned int pack2bf(float a, float b) {
    return (unsigned int)f2bf(a) | ((unsigned int)f2bf(b) << 16);
}
__device__ __forceinline__ float bf2f(unsigned int lo16) {
    return __uint_as_float(lo16 << 16);
}

// stage 16 rows x 64 bf16 from global (row-major 64) into LDS (stride 72)
__device__ __forceinline__ void stage_rows_bf16(const unsigned short* __restrict__ src,
                                                unsigned short* dst, int l) {
    int row = l >> 2, cq = (l & 3) * 16;
    const short8* s = (const short8*)(src + (size_t)row*64 + cq);
    short8* d0 = (short8*)(dst + row*72 + cq);
    d0[0] = s[0];
    d0[1] = s[1];
}

// stage 16 rows x 64 f32 from global into bf16 LDS (stride 72)
__device__ __forceinline__ void stage_rows_f32(const float* __restrict__ src,
                                               unsigned short* dst, int l) {
    int row = l >> 2, cq = (l & 3) * 16;
    const float4* s = (const float4*)(src + (size_t)row*64 + cq);
    unsigned int* d = (unsigned int*)(dst + row*72 + cq);
    #pragma unroll
    for (int i = 0; i < 4; ++i) {
        float4 f = s[i];
        d[i*2]   = pack2bf(f.x, f.y);
        d[i*2+1] = pack2bf(f.z, f.w);
    }
}

// ---------------------------------------------------------------------------
// K0: fold BNs; build all bf16 B-fragments + folded biases.
// B-frag layout (16x16x32): tile (ct,ks): frag[(ct*2+ks)*512 + l*8 + j] =
//   W[ks*32 + (l>>4)*8 + j][ct*16 + (l&15)]
// ---------------------------------------------------------------------------
__global__ __launch_bounds__(256) void k_prep(
    const float* __restrict__ pe_W1, const float* __restrict__ pe_b1, const float* __restrict__ pe_bn,
    const float* __restrict__ pe_W2, const float* __restrict__ pe_b2,
    const float* __restrict__ we_W1, const float* __restrict__ we_b1, const float* __restrict__ we_bn,
    const float* __restrict__ we_W2,
    const float* __restrict__ cg_W1, const float* __restrict__ cg_b1, const float* __restrict__ cg_bn,
    const float* __restrict__ Wq, const float* __restrict__ bq, const float* __restrict__ bnq,
    const float* __restrict__ Wk, const float* __restrict__ bk, const float* __restrict__ bnk,
    const float* __restrict__ Wv,
    float* __restrict__ peb1f, float* __restrict__ cvecg, float* __restrict__ cgb1f,
    float* __restrict__ biasqF, float* __restrict__ biaskF, float* __restrict__ cgW1cF,
    unsigned short* __restrict__ WqF, unsigned short* __restrict__ WkF, unsigned short* __restrict__ WvF,
    unsigned short* __restrict__ weW1F, unsigned short* __restrict__ cgW1aF,
    unsigned short* __restrict__ cgW1bF, unsigned short* __restrict__ cgW2F,
    unsigned short* __restrict__ W1frag, unsigned short* __restrict__ Wcfrag,
    unsigned short* __restrict__ W2frag)
{
    int t = threadIdx.x;
    __shared__ float sc1[64], csc[64], sqv[64], skv[64], wsc[8], wsh[8];
    __shared__ float sWe[64][8], sWb[8], sWc[64][8];
    if (t < 64) {
        float g = pe_bn[t], b = pe_bn[64+t], m = pe_bn[128+t], v = pe_bn[192+t];
        float s = g / sqrtf(v + EPSF);
        sc1[t] = s; peb1f[t] = pe_b1[t]*s + (b - m*s);
        g = cg_bn[t]; b = cg_bn[64+t]; m = cg_bn[128+t]; v = cg_bn[192+t];
        s = g / sqrtf(v + EPSF);
        csc[t] = s; cgb1f[t] = cg_b1[t]*s + (b - m*s);
        g = bnq[t]; b = bnq[64+t]; m = bnq[128+t]; v = bnq[192+t];
        s = g / sqrtf(v + EPSF);
        sqv[t] = s; biasqF[t] = bq[t]*s + (b - m*s);
        g = bnk[t]; b = bnk[64+t]; m = bnk[128+t]; v = bnk[192+t];
        s = g / sqrtf(v + EPSF);
        skv[t] = s; biaskF[t] = bk[t]*s + (b - m*s);
    }
    if (t < 8) {
        float g = we_bn[t], b = we_bn[8+t], m = we_bn[16+t], v = we_bn[24+t];
        float s = g / sqrtf(v + EPSF);
        wsc[t] = s; wsh[t] = b - m*s;
    }
    __syncthreads();
    for (int u = t; u < 512; u += 256) { int g = u & 7; sWe[u >> 3][g] = we_W1[u] * wsc[g]; }
    if (t < 8) sWb[t] = we_b1[t] * wsc[t] + wsh[t];
    __syncthreads();
    for (int u = t; u < 512; u += 256) {
        int h = u >> 3, g = u & 7;
        float a = 0.f;
        for (int c = 0; c < 64; ++c) a += pe_W2[h*64 + c] * sWe[c][g];
        sWc[h][g] = a;
    }
    if (t < 8) {
        float a = sWb[t];
        for (int c = 0; c < 64; ++c) a += pe_b2[c] * sWe[c][t];
        cvecg[t] = a;
    }
    __syncthreads();
    // 64x64 frags (8 tiles x 512)
    for (int u = t; u < 4096; u += 256) {
        int tile = u >> 9, l = (u >> 3) & 63, j = u & 7;
        int col = (tile >> 1)*16 + (l & 15);
        int kk  = (tile & 1)*32 + (l >> 4)*8 + j;
        WqF[u]    = f2bf(Wq[kk*64 + col] * sqv[col]);
        WkF[u]    = f2bf(Wk[kk*64 + col] * skv[col]);
        WvF[u]    = f2bf(Wv[kk*64 + col]);
        cgW1aF[u] = f2bf(cg_W1[kk*64 + col] * csc[col]);
        cgW1bF[u] = f2bf(cg_W1[(64 + kk)*64 + col] * csc[col]);
    }
    // 64->8 frags (2 tiles, cols padded to 16)
    for (int u = t; u < 1024; u += 256) {
        int tile = u >> 9, l = (u >> 3) & 63, j = u & 7;
        int col = l & 15;
        int kk  = tile*32 + (l >> 4)*8 + j;
        weW1F[u] = (col < 8) ? f2bf(sWe[kk][col]) : 0;
        cgW2F[u] = (col < 8) ? f2bf(we_W2 ? cg_W1 ? cg_W1[0]*0.f + 0.f : 0.f : 0.f) : 0; // placeholder (overwritten below)
    }
    // cgW2F properly (cg_W2 passed via cgW1cF trick not available; do here)
    __syncthreads();
    // cgW1cF: rows 128..191 of cg_W1, BN-folded, f32
    for (int u = t; u < 4096; u += 256) {
        int k = u >> 6, c = u & 63;
        cgW1cF[u] = cg_W1[(128 + k)*64 + c] * csc[c];
    }
    // k_main frags (same as verified R2)
    {
        int ct = t >> 6, l = t & 63;
        int col = 16*ct + (l & 15), kg = l >> 4;
        #pragma unroll
        for (int j = 0; j < 8; ++j) {
            int k = kg*8 + j;
            float v = (k < 28) ? pe_W1[k*64 + col] * sc1[col] : 0.f;
            W1frag[ct*512 + l*8 + j] = f2bf(v);
        }
    }
    if (t < 128) {
        int kg = t >> 6, l = t & 63, g = l & 15;
        #pragma unroll
        for (int j = 0; j < 8; ++j) {
            int k = kg*32 + (l >> 4)*8 + j;
            float v = (g < 8) ? sWc[k][g] : 0.f;
            Wcfrag[kg*512 + l*8 + j] = f2bf(v);
        }
    }
}

// small second prep kernel: cgW2F frag + W2frag (needs cg_W2/we_W2 cleanly)
__global__ __launch_bounds__(256) void k_prep2(
    const float* __restrict__ cg_W2, const float* __restrict__ we_W2,
    unsigned short* __restrict__ cgW2F, unsigned short* __restrict__ W2frag)
{
    int t = threadIdx.x;
    for (int u = t; u < 1024; u += 256) {
        int tile = u >> 9, l = (u >> 3) & 63, j = u & 7;
        int col = l & 15;
        int kk  = tile*32 + (l >> 4)*8 + j;
        cgW2F[u] = (col < 8) ? f2bf(cg_W2[kk*8 + col]) : 0;
    }
    if (t < 64) {
        int l = t, g = l & 15;
        #pragma unroll
        for (int j = 0; j < 8; ++j) {
            float v = (l < 16 && g < 8) ? we_W2[j*8 + g] : 0.f;
            W2frag[l*8 + j] = f2bf(v);
        }
    }
}

// ---------------------------------------------------------------------------
// K1: MFMA q/k/v. Block = 4 waves x 16 rows = 64 rows, wave-private LDS.
// Outputs: v_tbl f32, q_bf bf16, kw/qw f32, seg_max atomics. k never stored.
// ---------------------------------------------------------------------------
__global__ __launch_bounds__(256) void k_qkv(
    const float* __restrict__ feat, const int* __restrict__ offs,
    const unsigned short* __restrict__ WqF, const unsigned short* __restrict__ WkF,
    const unsigned short* __restrict__ WvF, const unsigned short* __restrict__ weW1F,
    const float* __restrict__ biasqF, const float* __restrict__ biaskF,
    const float* __restrict__ bv,
    float* __restrict__ v_tbl, unsigned short* __restrict__ q_bf,
    float* __restrict__ kw, float* __restrict__ qw, float* __restrict__ seg_max)
{
    __shared__ unsigned short sF[4][16*72];
    __shared__ unsigned short sQ[4][16*72];
    __shared__ unsigned short sK[4][16*72];
    __shared__ float sSeg[64];

    int t = threadIdx.x, w = t >> 6, l = t & 63;
    int lc = l & 15, lg = l >> 4;
    int rblk = blockIdx.x * 64;
    int r0 = rblk + w * 16;
    int o0 = offs[0], o1 = offs[1], o2 = offs[2];
    bool fast = seg_of(rblk, o0,o1,o2) == seg_of(rblk + 63, o0,o1,o2);

    if (t < 64) sSeg[t] = 0.f;
    __syncthreads();

    stage_rows_f32(feat + (size_t)r0*64, sF[w], l);
    short8 a0 = *(const short8*)(sF[w] + lc*72 + lg*8);
    short8 a1 = *(const short8*)(sF[w] + lc*72 + 32 + lg*8);

    float bqc[4], bkc[4], bvc[4];
    #pragma unroll
    for (int ct = 0; ct < 4; ++ct) {
        bqc[ct] = biasqF[ct*16 + lc];
        bkc[ct] = biaskF[ct*16 + lc];
        bvc[ct] = bv[ct*16 + lc];
    }

    // ---- q ----
    #pragma unroll
    for (int ct = 0; ct < 4; ++ct) {
        f32x4 z = {0.f,0.f,0.f,0.f};
        short8 b0 = *(const short8*)(WqF + (ct*2+0)*512 + l*8);
        short8 b1 = *(const short8*)(WqF + (ct*2+1)*512 + l*8);
        f32x4 c = __builtin_amdgcn_mfma_f32_16x16x32_bf16(a0, b0, z, 0,0,0);
        c = __builtin_amdgcn_mfma_f32_16x16x32_bf16(a1, b1, c, 0,0,0);
        float cmax = 0.f;
        #pragma unroll
        for (int reg = 0; reg < 4; ++reg) {
            float qv = fmaxf(c[reg] + bqc[ct], 0.f);
            sQ[w][(lg*4 + reg)*72 + ct*16 + lc] = f2bf(qv);
            if (fast) cmax = fmaxf(cmax, qv);
            else atomicMax((unsigned int*)&seg_max[seg_of(r0 + lg*4 + reg,o0,o1,o2)*64 + ct*16 + lc],
                           __float_as_uint(qv));
        }
        if (fast) {
            cmax = fmaxf(cmax, __shfl_xor(cmax, 16));
            cmax = fmaxf(cmax, __shfl_xor(cmax, 32));
            if (lg == 0)
                atomicMax((unsigned int*)&sSeg[ct*16 + lc], __float_as_uint(cmax));
        }
    }
    // ---- k ----
    #pragma unroll
    for (int ct = 0; ct < 4; ++ct) {
        f32x4 z = {0.f,0.f,0.f,0.f};
        short8 b0 = *(const short8*)(WkF + (ct*2+0)*512 + l*8);
        short8 b1 = *(const short8*)(WkF + (ct*2+1)*512 + l*8);
        f32x4 c = __builtin_amdgcn_mfma_f32_16x16x32_bf16(a0, b0, z, 0,0,0);
        c = __builtin_amdgcn_mfma_f32_16x16x32_bf16(a1, b1, c, 0,0,0);
        #pragma unroll
        for (int reg = 0; reg < 4; ++reg)
            sK[w][(lg*4 + reg)*72 + ct*16 + lc] = f2bf(fmaxf(c[reg] + bkc[ct], 0.f));
    }
    // ---- v ----
    #pragma unroll
    for (int ct = 0; ct < 4; ++ct) {
        f32x4 z = {0.f,0.f,0.f,0.f};
        short8 b0 = *(const short8*)(WvF + (ct*2+0)*512 + l*8);
        short8 b1 = *(const short8*)(WvF + (ct*2+1)*512 + l*8);
        f32x4 c = __builtin_amdgcn_mfma_f32_16x16x32_bf16(a0, b0, z, 0,0,0);
        c = __builtin_amdgcn_mfma_f32_16x16x32_bf16(a1, b1, c, 0,0,0);
        #pragma unroll
        for (int reg = 0; reg < 4; ++reg)
            v_tbl[(size_t)(r0 + lg*4 + reg)*64 + ct*16 + lc] = c[reg] + bvc[ct];
    }
    // ---- kw / qw via MFMA (K=64 -> 8 cols) ----
    {
        short8 wb0 = *(const short8*)(weW1F + l*8);
        short8 wb1 = *(const short8*)(weW1F + 512 + l*8);
        short8 aq0 = *(const short8*)(sQ[w] + lc*72 + lg*8);
        short8 aq1 = *(const short8*)(sQ[w] + lc*72 + 32 + lg*8);
        short8 ak0 = *(const short8*)(sK[w] + lc*72 + lg*8);
        short8 ak1 = *(const short8*)(sK[w] + lc*72 + 32 + lg*8);
        f32x4 z = {0.f,0.f,0.f,0.f};
        f32x4 cq = __builtin_amdgcn_mfma_f32_16x16x32_bf16(aq0, wb0, z, 0,0,0);
        cq = __builtin_amdgcn_mfma_f32_16x16x32_bf16(aq1, wb1, cq, 0,0,0);
        f32x4 ck = __builtin_amdgcn_mfma_f32_16x16x32_bf16(ak0, wb0, z, 0,0,0);
        ck = __builtin_amdgcn_mfma_f32_16x16x32_bf16(ak1, wb1, ck, 0,0,0);
        if (lc < 8) {
            #pragma unroll
            for (int reg = 0; reg < 4; ++reg) {
                qw[(size_t)(r0 + lg*4 + reg)*8 + lc] = cq[reg];
                kw[(size_t)(r0 + lg*4 + reg)*8 + lc] = ck[reg];
            }
        }
    }
    // ---- q_bf global write (vectorized via LDS reread) ----
    #pragma unroll
    for (int rep = 0; rep < 2; ++rep) {
        int row = (l >> 3) + rep*8;
        int ch = (l & 7) * 8;
        short8 vq = *(const short8*)(sQ[w] + row*72 + ch);
        *(short8*)(q_bf + (size_t)(r0 + row)*64 + ch) = vq;
    }
    __syncthreads();
    if (fast && t < 64)
        atomicMax((unsigned int*)&seg_max[seg_of(rblk,o0,o1,o2)*64 + t],
                  __float_as_uint(sSeg[t]));
}

// ---------------------------------------------------------------------------
// K_seg: gseg2[s][c] = cgb1f[c] + seg_max[s] @ cgW1cF. 1 block.
// ---------------------------------------------------------------------------
__global__ __launch_bounds__(256) void k_seg(
    const float* __restrict__ seg_max, const float* __restrict__ cgW1cF,
    const float* __restrict__ cgb1f, float* __restrict__ gseg2)
{
    int t = threadIdx.x;
    int c = t & 63, s = t >> 6;
    float a = cgb1f[c];
    for (int j = 0; j < 64; ++j) a += seg_max[s*64 + j] * cgW1cF[j*64 + c];
    gseg2[s*64 + c] = a;
}

// ---------------------------------------------------------------------------
// K2a: neighbor_ctx (bf16 gather-max). Block: 8 slots x 32 col-pairs, 64 rows.
// ---------------------------------------------------------------------------
__global__ __launch_bounds__(256) void k_nctx(
    const unsigned int* __restrict__ q_bf2, const int* __restrict__ ridx,
    unsigned int* __restrict__ nctx2)
{
    int t = threadIdx.x;
    int c = t & 31, slot = t >> 5;
    int n0 = blockIdx.x * 64 + slot * 8;
    for (int i = 0; i < 8; ++i) {
        int n = n0 + i;
        const int* ir = ridx + (size_t)n * 16;
        float m0 = 0.f, m1 = 0.f;
        #pragma unroll
        for (int kk = 0; kk < 16; ++kk) {
            int id = max(ir[kk], 0);
            unsigned int u = q_bf2[(size_t)id*32 + c];
            m0 = fmaxf(m0, bf2f(u & 0xffffu));
            m1 = fmaxf(m1, bf2f(u >> 16));
        }
        nctx2[(size_t)n*32 + c] = pack2bf(m0, m1);
    }
}

// ---------------------------------------------------------------------------
// K2b: gate MLP via MFMA. 4 waves x 16 rows, wave-private LDS.
// ---------------------------------------------------------------------------
__global__ __launch_bounds__(256) void k_gate(
    const unsigned short* __restrict__ q_bf, const unsigned short* __restrict__ nctx_bf,
    const unsigned short* __restrict__ cgW1aF, const unsigned short* __restrict__ cgW1bF,
    const unsigned short* __restrict__ cgW2F,
    const float* __restrict__ gseg2, const float* __restrict__ cg_b2,
    const int* __restrict__ offs,
    float* __restrict__ gate)
{
    __shared__ unsigned short sX[4][16*72];
    __shared__ unsigned short sH[4][16*72];
    int t = threadIdx.x, w = t >> 6, l = t & 63;
    int lc = l & 15, lg = l >> 4;
    int r0 = blockIdx.x * 64 + w * 16;
    int o0 = offs[0], o1 = offs[1], o2 = offs[2];

    stage_rows_bf16(q_bf + (size_t)r0*64, sX[w], l);
    short8 a0 = *(const short8*)(sX[w] + lc*72 + lg*8);
    short8 a1 = *(const short8*)(sX[w] + lc*72 + 32 + lg*8);

    f32x4 c4[4];
    #pragma unroll
    for (int ct = 0; ct < 4; ++ct) {
        #pragma unroll
        for (int reg = 0; reg < 4; ++reg)
            c4[ct][reg] = gseg2[seg_of(r0 + lg*4 + reg,o0,o1,o2)*64 + ct*16 + lc];
        short8 b0 = *(const short8*)(cgW1aF + (ct*2+0)*512 + l*8);
        short8 b1 = *(const short8*)(cgW1aF + (ct*2+1)*512 + l*8);
        c4[ct] = __builtin_amdgcn_mfma_f32_16x16x32_bf16(a0, b0, c4[ct], 0,0,0);
        c4[ct] = __builtin_amdgcn_mfma_f32_16x16x32_bf16(a1, b1, c4[ct], 0,0,0);
    }
    stage_rows_bf16(nctx_bf + (size_t)r0*64, sX[w], l);
    short8 n0v = *(const short8*)(sX[w] + lc*72 + lg*8);
    short8 n1v = *(const short8*)(sX[w] + lc*72 + 32 + lg*8);
    #pragma unroll
    for (int ct = 0; ct < 4; ++ct) {
        short8 b0 = *(const short8*)(cgW1bF + (ct*2+0)*512 + l*8);
        short8 b1 = *(const short8*)(cgW1bF + (ct*2+1)*512 + l*8);
        c4[ct] = __builtin_amdgcn_mfma_f32_16x16x32_bf16(n0v, b0, c4[ct], 0,0,0);
        c4[ct] = __builtin_amdgcn_mfma_f32_16x16x32_bf16(n1v, b1, c4[ct], 0,0,0);
        #pragma unroll
        for (int reg = 0; reg < 4; ++reg)
            sH[w][(lg*4 + reg)*72 + ct*16 + lc] = f2bf(fmaxf(c4[ct][reg], 0.f));
    }
    {
        short8 ah0 = *(const short8*)(sH[w] + lc*72 + lg*8);
        short8 ah1 = *(const short8*)(sH[w] + lc*72 + 32 + lg*8);
        short8 w0 = *(const short8*)(cgW2F + l*8);
        short8 w1 = *(const short8*)(cgW2F + 512 + l*8);
        float bg = cg_b2[lc & 7];
        f32x4 cg;
        #pragma unroll
        for (int reg = 0; reg < 4; ++reg) cg[reg] = bg;
        cg = __builtin_amdgcn_mfma_f32_16x16x32_bf16(ah0, w0, cg, 0,0,0);
        cg = __builtin_amdgcn_mfma_f32_16x16x32_bf16(ah1, w1, cg, 0,0,0);
        if (lc < 8) {
            #pragma unroll
            for (int reg = 0; reg < 4; ++reg)
                gate[(size_t)(r0 + lg*4 + reg)*8 + lc] = 1.f / (1.f + __expf(-cg[reg]));
        }
    }
}

// ---------------------------------------------------------------------------
// K3: unchanged verified MFMA pipeline from R2.
// ---------------------------------------------------------------------------
__global__ __launch_bounds__(64, 3) void k_main(
    const float* __restrict__ coord, const int* __restrict__ ridx,
    const float* __restrict__ v_tbl,
    const float* __restrict__ kw, const float* __restrict__ qw,
    const float* __restrict__ gate,
    const float* __restrict__ peb1f, const float* __restrict__ cvecg,
    const float* __restrict__ we_b2,
    const unsigned short* __restrict__ W1frag, const unsigned short* __restrict__ Wcfrag,
    const unsigned short* __restrict__ W2frag,
    float* __restrict__ out)
{
    __shared__ __align__(16) unsigned short sA1[64*40];
    __shared__ __align__(16) unsigned short sA2[64*72];
    __shared__ __align__(16) unsigned short sAh2[16*8];
    __shared__ float sAttn[4][16][8];
    __shared__ int sIds[64];

    int l = threadIdx.x;
    int pair = blockIdx.x * 64 + l;
    int nself = pair >> 4;

    int id = ridx[pair];
    sIds[l] = id;
    int ids = max(id, 0);

    {
        float cx = coord[nself*3], cy = coord[nself*3+1], cz = coord[nself*3+2];
        float dx = coord[ids*3]   - cx;
        float dy = coord[ids*3+1] - cy;
        float dz = coord[ids*3+2] - cz;
        float dist = sqrtf(dx*dx + dy*dy + dz*dz);
        unsigned int* row = (unsigned int*)sA1 + l*20;
        row[0] = pack2bf(dx, dy);
        row[1] = pack2bf(dz, dist);
        #pragma unroll
        for (int fi = 0; fi < 4; ++fi) {
            float fr = 3.14159265358979f * (float)(1 << fi);
            float sx, cxx, sy, cyy, sz, czz;
            __sincosf(dx * fr, &sx, &cxx);
            __sincosf(dy * fr, &sy, &cyy);
            __sincosf(dz * fr, &sz, &czz);
            row[2 + 2*fi] = pack2bf(sx, sy);
            row[3 + 2*fi] = pack2bf(cxx, cyy);
            row[10 + fi]  = pack2bf(sz, czz);
        }
        row[14] = 0u; row[15] = 0u;
    }

    int lc = l & 15, lg = l >> 4;

    short8 bW1[4], bWc[2], bW2;
    #pragma unroll
    for (int ct = 0; ct < 4; ++ct) bW1[ct] = *(const short8*)(W1frag + ct*512 + l*8);
    bWc[0] = *(const short8*)(Wcfrag + l*8);
    bWc[1] = *(const short8*)(Wcfrag + 512 + l*8);
    bW2 = *(const short8*)(W2frag + l*8);

    float bias1[4];
    #pragma unroll
    for (int ct = 0; ct < 4; ++ct) bias1[ct] = peb1f[16*ct + lc];
    int g7 = lc & 7;
    float cvec_g = cvecg[g7];
    float bias3 = we_b2[g7];

    #pragma unroll
    for (int rt = 0; rt < 4; ++rt) {
        int n = blockIdx.x * 4 + rt;
        short8 a1 = *(const short8*)(sA1 + (rt*16 + lc)*40 + lg*8);
        f32x4 c1[4];
        #pragma unroll
        for (int ct = 0; ct < 4; ++ct) {
            f32x4 z = {0.f, 0.f, 0.f, 0.f};
            c1[ct] = __builtin_amdgcn_mfma_f32_16x16x32_bf16(a1, bW1[ct], z, 0, 0, 0);
        }
        #pragma unroll
        for (int ct = 0; ct < 4; ++ct) {
            #pragma unroll
            for (int reg = 0; reg < 4; ++reg) {
                int r = rt*16 + lg*4 + reg;
                float h1 = fmaxf(c1[ct][reg] + bias1[ct], 0.f);
                sA2[r*72 + 16*ct + lc] = f2bf(h1);
            }
        }
        int ids_r[4];
        #pragma unroll
        for (int reg = 0; reg < 4; ++reg) ids_r[reg] = sIds[rt*16 + lg*4 + reg];
        float qwv = qw[(size_t)n*8 + g7];
        f32x4 c2;
        #pragma unroll
        for (int reg = 0; reg < 4; ++reg)
            c2[reg] = kw[(size_t)max(ids_r[reg],0)*8 + g7] - qwv + cvec_g;
        short8 a20 = *(const short8*)(sA2 + (rt*16 + lc)*72 + lg*8);
        short8 a21 = *(const short8*)(sA2 + (rt*16 + lc)*72 + 32 + lg*8);
        c2 = __builtin_amdgcn_mfma_f32_16x16x32_bf16(a20, bWc[0], c2, 0, 0, 0);
        c2 = __builtin_amdgcn_mfma_f32_16x16x32_bf16(a21, bWc[1], c2, 0, 0, 0);
        if (lc < 8) {
            #pragma unroll
            for (int reg = 0; reg < 4; ++reg)
                sAh2[(lg*4 + reg)*8 + lc] = f2bf(fmaxf(c2[reg], 0.f));
        }
        short8 a3 = {0,0,0,0,0,0,0,0};
        if (l < 16) a3 = *(const short8*)(sAh2 + lc*8);
        f32x4 c3;
        #pragma unroll
        for (int reg = 0; reg < 4; ++reg) c3[reg] = bias3;
        c3 = __builtin_amdgcn_mfma_f32_16x16x32_bf16(a3, bW2, c3, 0, 0, 0);
        float gv = gate[(size_t)n*8 + g7];
        float lgt[4];
        #pragma unroll
        for (int reg = 0; reg < 4; ++reg) lgt[reg] = c3[reg] * gv;
        float m = fmaxf(fmaxf(lgt[0], lgt[1]), fmaxf(lgt[2], lgt[3]));
        m = fmaxf(m, __shfl_xor(m, 16));
        m = fmaxf(m, __shfl_xor(m, 32));
        float e[4], s = 0.f;
        #pragma unroll
        for (int reg = 0; reg < 4; ++reg) { e[reg] = __expf(lgt[reg] - m); s += e[reg]; }
        s += __shfl_xor(s, 16);
        s += __shfl_xor(s, 32);
        float inv = 1.f / s;
        if (lc < 8) {
            #pragma unroll
            for (int reg = 0; reg < 4; ++reg) {
                int idv = ids_r[reg];
                float mf = (idv >= 0) ? 1.f : ((idv == -1) ? 0.f : -1.f);
                sAttn[rt][lg*4 + reg][lc] = e[reg] * inv * mf;
            }
        }
    }

    {
        int p = lg, kk = lc;
        int n2 = blockIdx.x * 4 + p;
        float4 o = make_float4(0.f, 0.f, 0.f, 0.f);
        int gh = kk >> 1;
        #pragma unroll
        for (int k2 = 0; k2 < 16; ++k2) {
            int id2 = max(sIds[p*16 + k2], 0);
            float a = sAttn[p][k2][gh];
            float4 vv = *(const float4*)(v_tbl + (size_t)id2*64 + kk*4);
            o.x += a*vv.x; o.y += a*vv.y; o.z += a*vv.z; o.w += a*vv.w;
        }
        *(float4*)(out + (size_t)n2*64 + kk*4) = o;
    }
}

// ---------------------------------------------------------------------------
extern "C" void kernel_launch(void* const* d_in, const int* in_sizes, int n_in,
                              void* d_out, int out_size, void* d_ws, size_t ws_size,
                              hipStream_t stream)
{
    const float* feat  = (const float*)d_in[0];
    const float* coord = (const float*)d_in[1];
    const int*   ridx  = (const int*)d_in[2];
    const int*   offs  = (const int*)d_in[3];
    const float* Wq = (const float*)d_in[4];  const float* bq = (const float*)d_in[5];  const float* bnq = (const float*)d_in[6];
    const float* Wk = (const float*)d_in[7];  const float* bk = (const float*)d_in[8];  const float* bnk = (const float*)d_in[9];
    const float* Wv = (const float*)d_in[10]; const float* bv = (const float*)d_in[11];
    const float* pe_W1 = (const float*)d_in[12]; const float* pe_b1 = (const float*)d_in[13]; const float* pe_bn = (const float*)d_in[14];
    const float* pe_W2 = (const float*)d_in[15]; const float* pe_b2 = (const float*)d_in[16];
    const float* we_W1 = (const float*)d_in[17]; const float* we_b1 = (const float*)d_in[18]; const float* we_bn = (const float*)d_in[19];
    const float* we_W2 = (const float*)d_in[20]; const float* we_b2 = (const float*)d_in[21];
    const float* cg_W1 = (const float*)d_in[22]; const float* cg_b1 = (const float*)d_in[23]; const float* cg_bn = (const float*)d_in[24];
    const float* cg_W2 = (const float*)d_in[25]; const float* cg_b2 = (const float*)d_in[26];
    float* out = (float*)d_out;
    int N = in_sizes[0] / 64;

    float* ws = (float*)d_ws;
    float* v_tbl = ws;                          // N*64
    float* kwp   = v_tbl + (size_t)N*64;        // N*8
    float* qwp   = kwp + (size_t)N*8;           // N*8
    float* gatep = qwp + (size_t)N*8;           // N*8
    float* segm  = gatep + (size_t)N*8;         // 256
    float* gseg2 = segm + 256;                  // 256
    float* peb1f = gseg2 + 256;                 // 64
    float* cvecg = peb1f + 64;                  // 8
    float* cgb1f = cvecg + 8;                   // 64
    float* biasqF= cgb1f + 64;                  // 64
    float* biaskF= biasqF + 64;                 // 64
    float* pad0  = biaskF + 64;                 // 56 (pad to 16B-multiple region)
    float* cgW1cF= pad0 + 56;                   // 4096
    unsigned short* q_bf    = (unsigned short*)(cgW1cF + 4096); // N*64
    unsigned short* nctx_bf = q_bf + (size_t)N*64;              // N*64
    unsigned short* WqF     = nctx_bf + (size_t)N*64;           // 4096
    unsigned short* WkF     = WqF + 4096;                       // 4096
    unsigned short* WvF     = WkF + 4096;                       // 4096
    unsigned short* weW1F   = WvF + 4096;                       // 1024
    unsigned short* cgW1aF  = weW1F + 1024;                     // 4096
    unsigned short* cgW1bF  = cgW1aF + 4096;                    // 4096
    unsigned short* cgW2F   = cgW1bF + 4096;                    // 1024
    unsigned short* W1frag  = cgW2F + 1024;                     // 2048
    unsigned short* Wcfrag  = W1frag + 2048;                    // 1024
    unsigned short* W2frag  = Wcfrag + 1024;                    // 512

    hipMemsetAsync(segm, 0, 256 * sizeof(float), stream);
    k_prep<<<1, 256, 0, stream>>>(pe_W1, pe_b1, pe_bn, pe_W2, pe_b2,
                                  we_W1, we_b1, we_bn, we_W2,
                                  cg_W1, cg_b1, cg_bn,
                                  Wq, bq, bnq, Wk, bk, bnk, Wv,
                                  peb1f, cvecg, cgb1f, biasqF, biaskF, cgW1cF,
                                  WqF, WkF, WvF, weW1F, cgW1aF, cgW1bF, cgW2F,
                                  W1frag, Wcfrag, W2frag);
    k_prep2<<<1, 256, 0, stream>>>(cg_W2, we_W2, cgW2F, W2frag);
    k_qkv<<<N/64, 256, 0, stream>>>(feat, offs, WqF, WkF, WvF, weW1F,
                                    biasqF, biaskF, bv,
                                    v_tbl, q_bf, kwp, qwp, segm);
    k_seg<<<1, 256, 0, stream>>>(segm, cgW1cF, cgb1f, gseg2);
    k_nctx<<<N/64, 256, 0, stream>>>((const unsigned int*)q_bf, ridx, (unsigned int*)nctx_bf);
    k_gate<<<N/64, 256, 0, stream>>>(q_bf, nctx_bf, cgW1aF, cgW1bF, cgW2F,
                                     gseg2, cg_b2, offs, gatep);
    k_main<<<N/4, 64, 0, stream>>>(coord, ridx, v_tbl, kwp, qwp, gatep,
                                   peb1f, cvecg, we_b2,
                                   W1frag, Wcfrag, W2frag, out);
}

// Round 4
// 121.981 us; speedup vs baseline: 7.0900x; 1.1372x over previous
//
#include <hip/hip_runtime.h>
#include <hip/hip_bf16.h>

#define EPSF 1e-5f

typedef __attribute__((ext_vector_type(8))) short short8;
typedef __attribute__((ext_vector_type(4))) float f32x4;

__device__ __forceinline__ int seg_of(int i, int o0, int o1, int o2) {
    return (i >= o0) + (i >= o1) + (i >= o2);
}

__device__ __forceinline__ unsigned short f2bf(float f) {
    unsigned int u = __float_as_uint(f);
    unsigned int r = (u + 0x7fffu + ((u >> 16) & 1u)) >> 16;
    return (unsigned short)r;
}
__device__ __forceinline__ unsigned int pack2bf(float a, float b) {
    return (unsigned int)f2bf(a) | ((unsigned int)f2bf(b) << 16);
}
__device__ __forceinline__ float bflo(unsigned int u) { return __uint_as_float(u << 16); }
__device__ __forceinline__ float bfhi(unsigned int u) { return __uint_as_float(u & 0xffff0000u); }

// stage 16 rows x 64 bf16 from global (row-major 64) into LDS (stride 72)
__device__ __forceinline__ void stage_rows_bf16(const unsigned short* __restrict__ src,
                                                unsigned short* dst, int l) {
    int row = l >> 2, cq = (l & 3) * 16;
    const short8* s = (const short8*)(src + (size_t)row*64 + cq);
    short8* d0 = (short8*)(dst + row*72 + cq);
    d0[0] = s[0];
    d0[1] = s[1];
}

// stage 16 rows x 64 f32 from global into bf16 LDS (stride 72)
__device__ __forceinline__ void stage_rows_f32(const float* __restrict__ src,
                                               unsigned short* dst, int l) {
    int row = l >> 2, cq = (l & 3) * 16;
    const float4* s = (const float4*)(src + (size_t)row*64 + cq);
    unsigned int* d = (unsigned int*)(dst + row*72 + cq);
    #pragma unroll
    for (int i = 0; i < 4; ++i) {
        float4 f = s[i];
        d[i*2]   = pack2bf(f.x, f.y);
        d[i*2+1] = pack2bf(f.z, f.w);
    }
}

// ---------------------------------------------------------------------------
// K0: fold BNs; build all bf16 B-fragments + folded biases.
// B-frag layout (16x16x32): tile (ct,ks): frag[(ct*2+ks)*512 + l*8 + j] =
//   W[ks*32 + (l>>4)*8 + j][ct*16 + (l&15)]
// ---------------------------------------------------------------------------
__global__ __launch_bounds__(256) void k_prep(
    const float* __restrict__ pe_W1, const float* __restrict__ pe_b1, const float* __restrict__ pe_bn,
    const float* __restrict__ pe_W2, const float* __restrict__ pe_b2,
    const float* __restrict__ we_W1, const float* __restrict__ we_b1, const float* __restrict__ we_bn,
    const float* __restrict__ cg_W1, const float* __restrict__ cg_b1, const float* __restrict__ cg_bn,
    const float* __restrict__ Wq, const float* __restrict__ bq, const float* __restrict__ bnq,
    const float* __restrict__ Wk, const float* __restrict__ bk, const float* __restrict__ bnk,
    const float* __restrict__ Wv,
    float* __restrict__ peb1f, float* __restrict__ cvecg, float* __restrict__ cgb1f,
    float* __restrict__ biasqF, float* __restrict__ biaskF, float* __restrict__ cgW1cF,
    unsigned short* __restrict__ WqF, unsigned short* __restrict__ WkF, unsigned short* __restrict__ WvF,
    unsigned short* __restrict__ weW1F, unsigned short* __restrict__ cgW1aF,
    unsigned short* __restrict__ cgW1bF,
    unsigned short* __restrict__ W1frag, unsigned short* __restrict__ Wcfrag)
{
    int t = threadIdx.x;
    __shared__ float sc1[64], csc[64], sqv[64], skv[64], wsc[8], wsh[8];
    __shared__ float sWe[64][8], sWb[8], sWc[64][8];
    if (t < 64) {
        float g = pe_bn[t], b = pe_bn[64+t], m = pe_bn[128+t], v = pe_bn[192+t];
        float s = g / sqrtf(v + EPSF);
        sc1[t] = s; peb1f[t] = pe_b1[t]*s + (b - m*s);
        g = cg_bn[t]; b = cg_bn[64+t]; m = cg_bn[128+t]; v = cg_bn[192+t];
        s = g / sqrtf(v + EPSF);
        csc[t] = s; cgb1f[t] = cg_b1[t]*s + (b - m*s);
        g = bnq[t]; b = bnq[64+t]; m = bnq[128+t]; v = bnq[192+t];
        s = g / sqrtf(v + EPSF);
        sqv[t] = s; biasqF[t] = bq[t]*s + (b - m*s);
        g = bnk[t]; b = bnk[64+t]; m = bnk[128+t]; v = bnk[192+t];
        s = g / sqrtf(v + EPSF);
        skv[t] = s; biaskF[t] = bk[t]*s + (b - m*s);
    }
    if (t < 8) {
        float g = we_bn[t], b = we_bn[8+t], m = we_bn[16+t], v = we_bn[24+t];
        float s = g / sqrtf(v + EPSF);
        wsc[t] = s; wsh[t] = b - m*s;
    }
    __syncthreads();
    for (int u = t; u < 512; u += 256) { int g = u & 7; sWe[u >> 3][g] = we_W1[u] * wsc[g]; }
    if (t < 8) sWb[t] = we_b1[t] * wsc[t] + wsh[t];
    __syncthreads();
    for (int u = t; u < 512; u += 256) {
        int h = u >> 3, g = u & 7;
        float a = 0.f;
        for (int c = 0; c < 64; ++c) a += pe_W2[h*64 + c] * sWe[c][g];
        sWc[h][g] = a;
    }
    if (t < 8) {
        float a = sWb[t];
        for (int c = 0; c < 64; ++c) a += pe_b2[c] * sWe[c][t];
        cvecg[t] = a;
    }
    __syncthreads();
    // 64x64 frags (8 tiles x 512)
    for (int u = t; u < 4096; u += 256) {
        int tile = u >> 9, l = (u >> 3) & 63, j = u & 7;
        int col = (tile >> 1)*16 + (l & 15);
        int kk  = (tile & 1)*32 + (l >> 4)*8 + j;
        WqF[u]    = f2bf(Wq[kk*64 + col] * sqv[col]);
        WkF[u]    = f2bf(Wk[kk*64 + col] * skv[col]);
        WvF[u]    = f2bf(Wv[kk*64 + col]);
        cgW1aF[u] = f2bf(cg_W1[kk*64 + col] * csc[col]);
        cgW1bF[u] = f2bf(cg_W1[(64 + kk)*64 + col] * csc[col]);
    }
    // 64->8 frags (2 tiles, cols padded to 16)
    for (int u = t; u < 1024; u += 256) {
        int tile = u >> 9, l = (u >> 3) & 63, j = u & 7;
        int col = l & 15;
        int kk  = tile*32 + (l >> 4)*8 + j;
        weW1F[u] = (col < 8) ? f2bf(sWe[kk][col]) : 0;
    }
    // cgW1cF: rows 128..191 of cg_W1, BN-folded, f32
    for (int u = t; u < 4096; u += 256) {
        int k = u >> 6, c = u & 63;
        cgW1cF[u] = cg_W1[(128 + k)*64 + c] * csc[c];
    }
    // k_main frags
    {
        int ct = t >> 6, l = t & 63;
        int col = 16*ct + (l & 15), kg = l >> 4;
        #pragma unroll
        for (int j = 0; j < 8; ++j) {
            int k = kg*8 + j;
            float v = (k < 28) ? pe_W1[k*64 + col] * sc1[col] : 0.f;
            W1frag[ct*512 + l*8 + j] = f2bf(v);
        }
    }
    if (t < 128) {
        int kg = t >> 6, l = t & 63, g = l & 15;
        #pragma unroll
        for (int j = 0; j < 8; ++j) {
            int k = kg*32 + (l >> 4)*8 + j;
            float v = (g < 8) ? sWc[k][g] : 0.f;
            Wcfrag[kg*512 + l*8 + j] = f2bf(v);
        }
    }
}

// second prep kernel: cgW2F frag + W2frag
__global__ __launch_bounds__(256) void k_prep2(
    const float* __restrict__ cg_W2, const float* __restrict__ we_W2,
    unsigned short* __restrict__ cgW2F, unsigned short* __restrict__ W2frag)
{
    int t = threadIdx.x;
    for (int u = t; u < 1024; u += 256) {
        int tile = u >> 9, l = (u >> 3) & 63, j = u & 7;
        int col = l & 15;
        int kk  = tile*32 + (l >> 4)*8 + j;
        cgW2F[u] = (col < 8) ? f2bf(cg_W2[kk*8 + col]) : 0;
    }
    if (t < 64) {
        int l = t, g = l & 15;
        #pragma unroll
        for (int j = 0; j < 8; ++j) {
            float v = (l < 16 && g < 8) ? we_W2[j*8 + g] : 0.f;
            W2frag[l*8 + j] = f2bf(v);
        }
    }
}

// ---------------------------------------------------------------------------
// K1: MFMA q/k/v. Block = 4 waves x 16 rows = 64 rows, wave-private LDS.
// Outputs: v_bf bf16, q_bf bf16, kw/qw f32, seg_max atomics. k never stored.
// ---------------------------------------------------------------------------
__global__ __launch_bounds__(256) void k_qkv(
    const float* __restrict__ feat, const int* __restrict__ offs,
    const unsigned short* __restrict__ WqF, const unsigned short* __restrict__ WkF,
    const unsigned short* __restrict__ WvF, const unsigned short* __restrict__ weW1F,
    const float* __restrict__ biasqF, const float* __restrict__ biaskF,
    const float* __restrict__ bv,
    unsigned short* __restrict__ v_bf, unsigned short* __restrict__ q_bf,
    float* __restrict__ kw, float* __restrict__ qw, float* __restrict__ seg_max)
{
    __shared__ unsigned short sF[4][16*72];
    __shared__ unsigned short sQ[4][16*72];
    __shared__ unsigned short sK[4][16*72];
    __shared__ float sSeg[64];

    int t = threadIdx.x, w = t >> 6, l = t & 63;
    int lc = l & 15, lg = l >> 4;
    int rblk = blockIdx.x * 64;
    int r0 = rblk + w * 16;
    int o0 = offs[0], o1 = offs[1], o2 = offs[2];
    bool fast = seg_of(rblk, o0,o1,o2) == seg_of(rblk + 63, o0,o1,o2);

    if (t < 64) sSeg[t] = 0.f;
    __syncthreads();

    stage_rows_f32(feat + (size_t)r0*64, sF[w], l);
    short8 a0 = *(const short8*)(sF[w] + lc*72 + lg*8);
    short8 a1 = *(const short8*)(sF[w] + lc*72 + 32 + lg*8);

    float bqc[4], bkc[4], bvc[4];
    #pragma unroll
    for (int ct = 0; ct < 4; ++ct) {
        bqc[ct] = biasqF[ct*16 + lc];
        bkc[ct] = biaskF[ct*16 + lc];
        bvc[ct] = bv[ct*16 + lc];
    }

    // ---- q ----
    #pragma unroll
    for (int ct = 0; ct < 4; ++ct) {
        f32x4 z = {0.f,0.f,0.f,0.f};
        short8 b0 = *(const short8*)(WqF + (ct*2+0)*512 + l*8);
        short8 b1 = *(const short8*)(WqF + (ct*2+1)*512 + l*8);
        f32x4 c = __builtin_amdgcn_mfma_f32_16x16x32_bf16(a0, b0, z, 0,0,0);
        c = __builtin_amdgcn_mfma_f32_16x16x32_bf16(a1, b1, c, 0,0,0);
        float cmax = 0.f;
        #pragma unroll
        for (int reg = 0; reg < 4; ++reg) {
            float qv = fmaxf(c[reg] + bqc[ct], 0.f);
            sQ[w][(lg*4 + reg)*72 + ct*16 + lc] = f2bf(qv);
            if (fast) cmax = fmaxf(cmax, qv);
            else atomicMax((unsigned int*)&seg_max[seg_of(r0 + lg*4 + reg,o0,o1,o2)*64 + ct*16 + lc],
                           __float_as_uint(qv));
        }
        if (fast) {
            cmax = fmaxf(cmax, __shfl_xor(cmax, 16));
            cmax = fmaxf(cmax, __shfl_xor(cmax, 32));
            if (lg == 0)
                atomicMax((unsigned int*)&sSeg[ct*16 + lc], __float_as_uint(cmax));
        }
    }
    // ---- k ----
    #pragma unroll
    for (int ct = 0; ct < 4; ++ct) {
        f32x4 z = {0.f,0.f,0.f,0.f};
        short8 b0 = *(const short8*)(WkF + (ct*2+0)*512 + l*8);
        short8 b1 = *(const short8*)(WkF + (ct*2+1)*512 + l*8);
        f32x4 c = __builtin_amdgcn_mfma_f32_16x16x32_bf16(a0, b0, z, 0,0,0);
        c = __builtin_amdgcn_mfma_f32_16x16x32_bf16(a1, b1, c, 0,0,0);
        #pragma unroll
        for (int reg = 0; reg < 4; ++reg)
            sK[w][(lg*4 + reg)*72 + ct*16 + lc] = f2bf(fmaxf(c[reg] + bkc[ct], 0.f));
    }
    // ---- v (staged bf16 into sF, which is dead now) ----
    #pragma unroll
    for (int ct = 0; ct < 4; ++ct) {
        f32x4 z = {0.f,0.f,0.f,0.f};
        short8 b0 = *(const short8*)(WvF + (ct*2+0)*512 + l*8);
        short8 b1 = *(const short8*)(WvF + (ct*2+1)*512 + l*8);
        f32x4 c = __builtin_amdgcn_mfma_f32_16x16x32_bf16(a0, b0, z, 0,0,0);
        c = __builtin_amdgcn_mfma_f32_16x16x32_bf16(a1, b1, c, 0,0,0);
        #pragma unroll
        for (int reg = 0; reg < 4; ++reg)
            sF[w][(lg*4 + reg)*72 + ct*16 + lc] = f2bf(c[reg] + bvc[ct]);
    }
    // ---- kw / qw via MFMA (K=64 -> 8 cols) ----
    {
        short8 wb0 = *(const short8*)(weW1F + l*8);
        short8 wb1 = *(const short8*)(weW1F + 512 + l*8);
        short8 aq0 = *(const short8*)(sQ[w] + lc*72 + lg*8);
        short8 aq1 = *(const short8*)(sQ[w] + lc*72 + 32 + lg*8);
        short8 ak0 = *(const short8*)(sK[w] + lc*72 + lg*8);
        short8 ak1 = *(const short8*)(sK[w] + lc*72 + 32 + lg*8);
        f32x4 z = {0.f,0.f,0.f,0.f};
        f32x4 cq = __builtin_amdgcn_mfma_f32_16x16x32_bf16(aq0, wb0, z, 0,0,0);
        cq = __builtin_amdgcn_mfma_f32_16x16x32_bf16(aq1, wb1, cq, 0,0,0);
        f32x4 ck = __builtin_amdgcn_mfma_f32_16x16x32_bf16(ak0, wb0, z, 0,0,0);
        ck = __builtin_amdgcn_mfma_f32_16x16x32_bf16(ak1, wb1, ck, 0,0,0);
        if (lc < 8) {
            #pragma unroll
            for (int reg = 0; reg < 4; ++reg) {
                qw[(size_t)(r0 + lg*4 + reg)*8 + lc] = cq[reg];
                kw[(size_t)(r0 + lg*4 + reg)*8 + lc] = ck[reg];
            }
        }
    }
    // ---- q_bf / v_bf global writes (vectorized via LDS reread) ----
    #pragma unroll
    for (int rep = 0; rep < 2; ++rep) {
        int row = (l >> 3) + rep*8;
        int ch = (l & 7) * 8;
        short8 vq = *(const short8*)(sQ[w] + row*72 + ch);
        *(short8*)(q_bf + (size_t)(r0 + row)*64 + ch) = vq;
        short8 vv = *(const short8*)(sF[w] + row*72 + ch);
        *(short8*)(v_bf + (size_t)(r0 + row)*64 + ch) = vv;
    }
    __syncthreads();
    if (fast && t < 64)
        atomicMax((unsigned int*)&seg_max[seg_of(rblk,o0,o1,o2)*64 + t],
                  __float_as_uint(sSeg[t]));
}

// ---------------------------------------------------------------------------
// K_seg: gseg2[s][c] = cgb1f[c] + seg_max[s] @ cgW1cF. 1 block.
// ---------------------------------------------------------------------------
__global__ __launch_bounds__(256) void k_seg(
    const float* __restrict__ seg_max, const float* __restrict__ cgW1cF,
    const float* __restrict__ cgb1f, float* __restrict__ gseg2)
{
    int t = threadIdx.x;
    int c = t & 63, s = t >> 6;
    float a = cgb1f[c];
    for (int j = 0; j < 64; ++j) a += seg_max[s*64 + j] * cgW1cF[j*64 + c];
    gseg2[s*64 + c] = a;
}

// ---------------------------------------------------------------------------
// K2: gate MLP via MFMA with fused neighbor-max gather.
// 4 waves x 16 rows, wave-private LDS.
// ---------------------------------------------------------------------------
__global__ __launch_bounds__(256) void k_gate(
    const unsigned short* __restrict__ q_bf, const int* __restrict__ ridx,
    const unsigned short* __restrict__ cgW1aF, const unsigned short* __restrict__ cgW1bF,
    const unsigned short* __restrict__ cgW2F,
    const float* __restrict__ gseg2, const float* __restrict__ cg_b2,
    const int* __restrict__ offs,
    float* __restrict__ gate)
{
    __shared__ unsigned short sX[4][16*72];   // q rows, later reused for H
    __shared__ unsigned short sN[4][16*72];   // nctx rows
    __shared__ int sIdx[4][256];
    int t = threadIdx.x, w = t >> 6, l = t & 63;
    int lc = l & 15, lg = l >> 4;
    int r0 = blockIdx.x * 64 + w * 16;
    int o0 = offs[0], o1 = offs[1], o2 = offs[2];

    stage_rows_bf16(q_bf + (size_t)r0*64, sX[w], l);
    #pragma unroll
    for (int i = 0; i < 4; ++i)
        sIdx[w][l*4 + i] = ridx[(size_t)r0*16 + l*4 + i];

    short8 a0 = *(const short8*)(sX[w] + lc*72 + lg*8);
    short8 a1 = *(const short8*)(sX[w] + lc*72 + 32 + lg*8);

    // ---- fused neighbor-max: lane handles row l>>2, cols (l&3)*16..+15 ----
    {
        int row = l >> 2, cq = (l & 3) * 16;
        float m[16];
        #pragma unroll
        for (int i = 0; i < 16; ++i) m[i] = 0.f;
        for (int k = 0; k < 16; ++k) {
            int id = max(sIdx[w][row*16 + k], 0);
            const uint4* p = (const uint4*)(q_bf + (size_t)id*64 + cq);
            uint4 u0 = p[0], u1 = p[1];
            m[0]  = fmaxf(m[0],  bflo(u0.x)); m[1]  = fmaxf(m[1],  bfhi(u0.x));
            m[2]  = fmaxf(m[2],  bflo(u0.y)); m[3]  = fmaxf(m[3],  bfhi(u0.y));
            m[4]  = fmaxf(m[4],  bflo(u0.z)); m[5]  = fmaxf(m[5],  bfhi(u0.z));
            m[6]  = fmaxf(m[6],  bflo(u0.w)); m[7]  = fmaxf(m[7],  bfhi(u0.w));
            m[8]  = fmaxf(m[8],  bflo(u1.x)); m[9]  = fmaxf(m[9],  bfhi(u1.x));
            m[10] = fmaxf(m[10], bflo(u1.y)); m[11] = fmaxf(m[11], bfhi(u1.y));
            m[12] = fmaxf(m[12], bflo(u1.z)); m[13] = fmaxf(m[13], bfhi(u1.z));
            m[14] = fmaxf(m[14], bflo(u1.w)); m[15] = fmaxf(m[15], bfhi(u1.w));
        }
        unsigned int* d = (unsigned int*)(sN[w] + row*72 + cq);
        #pragma unroll
        for (int i = 0; i < 8; ++i) d[i] = pack2bf(m[2*i], m[2*i+1]);
    }

    f32x4 c4[4];
    #pragma unroll
    for (int ct = 0; ct < 4; ++ct) {
        #pragma unroll
        for (int reg = 0; reg < 4; ++reg)
            c4[ct][reg] = gseg2[seg_of(r0 + lg*4 + reg,o0,o1,o2)*64 + ct*16 + lc];
        short8 b0 = *(const short8*)(cgW1aF + (ct*2+0)*512 + l*8);
        short8 b1 = *(const short8*)(cgW1aF + (ct*2+1)*512 + l*8);
        c4[ct] = __builtin_amdgcn_mfma_f32_16x16x32_bf16(a0, b0, c4[ct], 0,0,0);
        c4[ct] = __builtin_amdgcn_mfma_f32_16x16x32_bf16(a1, b1, c4[ct], 0,0,0);
    }
    short8 n0v = *(const short8*)(sN[w] + lc*72 + lg*8);
    short8 n1v = *(const short8*)(sN[w] + lc*72 + 32 + lg*8);
    #pragma unroll
    for (int ct = 0; ct < 4; ++ct) {
        short8 b0 = *(const short8*)(cgW1bF + (ct*2+0)*512 + l*8);
        short8 b1 = *(const short8*)(cgW1bF + (ct*2+1)*512 + l*8);
        c4[ct] = __builtin_amdgcn_mfma_f32_16x16x32_bf16(n0v, b0, c4[ct], 0,0,0);
        c4[ct] = __builtin_amdgcn_mfma_f32_16x16x32_bf16(n1v, b1, c4[ct], 0,0,0);
        #pragma unroll
        for (int reg = 0; reg < 4; ++reg)
            sX[w][(lg*4 + reg)*72 + ct*16 + lc] = f2bf(fmaxf(c4[ct][reg], 0.f));
    }
    {
        short8 ah0 = *(const short8*)(sX[w] + lc*72 + lg*8);
        short8 ah1 = *(const short8*)(sX[w] + lc*72 + 32 + lg*8);
        short8 w0 = *(const short8*)(cgW2F + l*8);
        short8 w1 = *(const short8*)(cgW2F + 512 + l*8);
        float bg = cg_b2[lc & 7];
        f32x4 cg;
        #pragma unroll
        for (int reg = 0; reg < 4; ++reg) cg[reg] = bg;
        cg = __builtin_amdgcn_mfma_f32_16x16x32_bf16(ah0, w0, cg, 0,0,0);
        cg = __builtin_amdgcn_mfma_f32_16x16x32_bf16(ah1, w1, cg, 0,0,0);
        if (lc < 8) {
            #pragma unroll
            for (int reg = 0; reg < 4; ++reg)
                gate[(size_t)(r0 + lg*4 + reg)*8 + lc] = 1.f / (1.f + __expf(-cg[reg]));
        }
    }
}

// ---------------------------------------------------------------------------
// K3: MFMA pipeline (verified), v gather now bf16.
// ---------------------------------------------------------------------------
__global__ __launch_bounds__(64, 3) void k_main(
    const float* __restrict__ coord, const int* __restrict__ ridx,
    const unsigned short* __restrict__ v_bf,
    const float* __restrict__ kw, const float* __restrict__ qw,
    const float* __restrict__ gate,
    const float* __restrict__ peb1f, const float* __restrict__ cvecg,
    const float* __restrict__ we_b2,
    const unsigned short* __restrict__ W1frag, const unsigned short* __restrict__ Wcfrag,
    const unsigned short* __restrict__ W2frag,
    float* __restrict__ out)
{
    __shared__ __align__(16) unsigned short sA1[64*40];
    __shared__ __align__(16) unsigned short sA2[64*72];
    __shared__ __align__(16) unsigned short sAh2[16*8];
    __shared__ float sAttn[4][16][8];
    __shared__ int sIds[64];

    int l = threadIdx.x;
    int pair = blockIdx.x * 64 + l;
    int nself = pair >> 4;

    int id = ridx[pair];
    sIds[l] = id;
    int ids = max(id, 0);

    {
        float cx = coord[nself*3], cy = coord[nself*3+1], cz = coord[nself*3+2];
        float dx = coord[ids*3]   - cx;
        float dy = coord[ids*3+1] - cy;
        float dz = coord[ids*3+2] - cz;
        float dist = sqrtf(dx*dx + dy*dy + dz*dz);
        unsigned int* row = (unsigned int*)sA1 + l*20;
        row[0] = pack2bf(dx, dy);
        row[1] = pack2bf(dz, dist);
        #pragma unroll
        for (int fi = 0; fi < 4; ++fi) {
            float fr = 3.14159265358979f * (float)(1 << fi);
            float sx, cxx, sy, cyy, sz, czz;
            __sincosf(dx * fr, &sx, &cxx);
            __sincosf(dy * fr, &sy, &cyy);
            __sincosf(dz * fr, &sz, &czz);
            row[2 + 2*fi] = pack2bf(sx, sy);
            row[3 + 2*fi] = pack2bf(cxx, cyy);
            row[10 + fi]  = pack2bf(sz, czz);
        }
        row[14] = 0u; row[15] = 0u;
    }

    int lc = l & 15, lg = l >> 4;

    short8 bW1[4], bWc[2], bW2;
    #pragma unroll
    for (int ct = 0; ct < 4; ++ct) bW1[ct] = *(const short8*)(W1frag + ct*512 + l*8);
    bWc[0] = *(const short8*)(Wcfrag + l*8);
    bWc[1] = *(const short8*)(Wcfrag + 512 + l*8);
    bW2 = *(const short8*)(W2frag + l*8);

    float bias1[4];
    #pragma unroll
    for (int ct = 0; ct < 4; ++ct) bias1[ct] = peb1f[16*ct + lc];
    int g7 = lc & 7;
    float cvec_g = cvecg[g7];
    float bias3 = we_b2[g7];

    #pragma unroll
    for (int rt = 0; rt < 4; ++rt) {
        int n = blockIdx.x * 4 + rt;
        short8 a1 = *(const short8*)(sA1 + (rt*16 + lc)*40 + lg*8);
        f32x4 c1[4];
        #pragma unroll
        for (int ct = 0; ct < 4; ++ct) {
            f32x4 z = {0.f, 0.f, 0.f, 0.f};
            c1[ct] = __builtin_amdgcn_mfma_f32_16x16x32_bf16(a1, bW1[ct], z, 0, 0, 0);
        }
        #pragma unroll
        for (int ct = 0; ct < 4; ++ct) {
            #pragma unroll
            for (int reg = 0; reg < 4; ++reg) {
                int r = rt*16 + lg*4 + reg;
                float h1 = fmaxf(c1[ct][reg] + bias1[ct], 0.f);
                sA2[r*72 + 16*ct + lc] = f2bf(h1);
            }
        }
        int ids_r[4];
        #pragma unroll
        for (int reg = 0; reg < 4; ++reg) ids_r[reg] = sIds[rt*16 + lg*4 + reg];
        float qwv = qw[(size_t)n*8 + g7];
        f32x4 c2;
        #pragma unroll
        for (int reg = 0; reg < 4; ++reg)
            c2[reg] = kw[(size_t)max(ids_r[reg],0)*8 + g7] - qwv + cvec_g;
        short8 a20 = *(const short8*)(sA2 + (rt*16 + lc)*72 + lg*8);
        short8 a21 = *(const short8*)(sA2 + (rt*16 + lc)*72 + 32 + lg*8);
        c2 = __builtin_amdgcn_mfma_f32_16x16x32_bf16(a20, bWc[0], c2, 0, 0, 0);
        c2 = __builtin_amdgcn_mfma_f32_16x16x32_bf16(a21, bWc[1], c2, 0, 0, 0);
        if (lc < 8) {
            #pragma unroll
            for (int reg = 0; reg < 4; ++reg)
                sAh2[(lg*4 + reg)*8 + lc] = f2bf(fmaxf(c2[reg], 0.f));
        }
        short8 a3 = {0,0,0,0,0,0,0,0};
        if (l < 16) a3 = *(const short8*)(sAh2 + lc*8);
        f32x4 c3;
        #pragma unroll
        for (int reg = 0; reg < 4; ++reg) c3[reg] = bias3;
        c3 = __builtin_amdgcn_mfma_f32_16x16x32_bf16(a3, bW2, c3, 0, 0, 0);
        float gv = gate[(size_t)n*8 + g7];
        float lgt[4];
        #pragma unroll
        for (int reg = 0; reg < 4; ++reg) lgt[reg] = c3[reg] * gv;
        float m = fmaxf(fmaxf(lgt[0], lgt[1]), fmaxf(lgt[2], lgt[3]));
        m = fmaxf(m, __shfl_xor(m, 16));
        m = fmaxf(m, __shfl_xor(m, 32));
        float e[4], s = 0.f;
        #pragma unroll
        for (int reg = 0; reg < 4; ++reg) { e[reg] = __expf(lgt[reg] - m); s += e[reg]; }
        s += __shfl_xor(s, 16);
        s += __shfl_xor(s, 32);
        float inv = 1.f / s;
        if (lc < 8) {
            #pragma unroll
            for (int reg = 0; reg < 4; ++reg) {
                int idv = ids_r[reg];
                float mf = (idv >= 0) ? 1.f : ((idv == -1) ? 0.f : -1.f);
                sAttn[rt][lg*4 + reg][lc] = e[reg] * inv * mf;
            }
        }
    }

    {
        int p = lg, kk = lc;
        int n2 = blockIdx.x * 4 + p;
        float4 o = make_float4(0.f, 0.f, 0.f, 0.f);
        int gh = kk >> 1;
        #pragma unroll
        for (int k2 = 0; k2 < 16; ++k2) {
            int id2 = max(sIds[p*16 + k2], 0);
            float a = sAttn[p][k2][gh];
            uint2 u = *(const uint2*)(v_bf + (size_t)id2*64 + kk*4);
            o.x += a * bflo(u.x); o.y += a * bfhi(u.x);
            o.z += a * bflo(u.y); o.w += a * bfhi(u.y);
        }
        *(float4*)(out + (size_t)n2*64 + kk*4) = o;
    }
}

// ---------------------------------------------------------------------------
extern "C" void kernel_launch(void* const* d_in, const int* in_sizes, int n_in,
                              void* d_out, int out_size, void* d_ws, size_t ws_size,
                              hipStream_t stream)
{
    const float* feat  = (const float*)d_in[0];
    const float* coord = (const float*)d_in[1];
    const int*   ridx  = (const int*)d_in[2];
    const int*   offs  = (const int*)d_in[3];
    const float* Wq = (const float*)d_in[4];  const float* bq = (const float*)d_in[5];  const float* bnq = (const float*)d_in[6];
    const float* Wk = (const float*)d_in[7];  const float* bk = (const float*)d_in[8];  const float* bnk = (const float*)d_in[9];
    const float* Wv = (const float*)d_in[10]; const float* bv = (const float*)d_in[11];
    const float* pe_W1 = (const float*)d_in[12]; const float* pe_b1 = (const float*)d_in[13]; const float* pe_bn = (const float*)d_in[14];
    const float* pe_W2 = (const float*)d_in[15]; const float* pe_b2 = (const float*)d_in[16];
    const float* we_W1 = (const float*)d_in[17]; const float* we_b1 = (const float*)d_in[18]; const float* we_bn = (const float*)d_in[19];
    const float* we_W2 = (const float*)d_in[20]; const float* we_b2 = (const float*)d_in[21];
    const float* cg_W1 = (const float*)d_in[22]; const float* cg_b1 = (const float*)d_in[23]; const float* cg_bn = (const float*)d_in[24];
    const float* cg_W2 = (const float*)d_in[25]; const float* cg_b2 = (const float*)d_in[26];
    float* out = (float*)d_out;
    int N = in_sizes[0] / 64;

    // bf16 tables first (16B aligned at ws base)
    unsigned short* v_bf = (unsigned short*)d_ws;               // N*64
    unsigned short* q_bf = v_bf + (size_t)N*64;                 // N*64
    float* kwp   = (float*)(q_bf + (size_t)N*64);               // N*8
    float* qwp   = kwp + (size_t)N*8;                           // N*8
    float* gatep = qwp + (size_t)N*8;                           // N*8
    float* segm  = gatep + (size_t)N*8;                         // 256
    float* gseg2 = segm + 256;                                  // 256
    float* peb1f = gseg2 + 256;                                 // 64
    float* cvecg = peb1f + 64;                                  // 8
    float* cgb1f = cvecg + 8;                                   // 64
    float* biasqF= cgb1f + 64;                                  // 64
    float* biaskF= biasqF + 64;                                 // 64
    float* pad0  = biaskF + 64;                                 // 56 pad
    float* cgW1cF= pad0 + 56;                                   // 4096
    unsigned short* WqF     = (unsigned short*)(cgW1cF + 4096); // 4096
    unsigned short* WkF     = WqF + 4096;                       // 4096
    unsigned short* WvF     = WkF + 4096;                       // 4096
    unsigned short* weW1F   = WvF + 4096;                       // 1024
    unsigned short* cgW1aF  = weW1F + 1024;                     // 4096
    unsigned short* cgW1bF  = cgW1aF + 4096;                    // 4096
    unsigned short* cgW2F   = cgW1bF + 4096;                    // 1024
    unsigned short* W1frag  = cgW2F + 1024;                     // 2048
    unsigned short* Wcfrag  = W1frag + 2048;                    // 1024
    unsigned short* W2frag  = Wcfrag + 1024;                    // 512

    hipMemsetAsync(segm, 0, 256 * sizeof(float), stream);
    k_prep<<<1, 256, 0, stream>>>(pe_W1, pe_b1, pe_bn, pe_W2, pe_b2,
                                  we_W1, we_b1, we_bn,
                                  cg_W1, cg_b1, cg_bn,
                                  Wq, bq, bnq, Wk, bk, bnk, Wv,
                                  peb1f, cvecg, cgb1f, biasqF, biaskF, cgW1cF,
                                  WqF, WkF, WvF, weW1F, cgW1aF, cgW1bF,
                                  W1frag, Wcfrag);
    k_prep2<<<1, 256, 0, stream>>>(cg_W2, we_W2, cgW2F, W2frag);
    k_qkv<<<N/64, 256, 0, stream>>>(feat, offs, WqF, WkF, WvF, weW1F,
                                    biasqF, biaskF, bv,
                                    v_bf, q_bf, kwp, qwp, segm);
    k_seg<<<1, 256, 0, stream>>>(segm, cgW1cF, cgb1f, gseg2);
    k_gate<<<N/64, 256, 0, stream>>>(q_bf, ridx, cgW1aF, cgW1bF, cgW2F,
                                     gseg2, cg_b2, offs, gatep);
    k_main<<<N/4, 64, 0, stream>>>(coord, ridx, v_bf, kwp, qwp, gatep,
                                   peb1f, cvecg, we_b2,
                                   W1frag, Wcfrag, W2frag, out);
}